// Round 1
// baseline (11035.975 us; speedup 1.0000x reference)
//
#include <hip/hip_runtime.h>
#include <math.h>

// Problem constants
#define NN   307
#define TT   256
#define HHH  64
#define NROW (NN*TT)     // 78592
#define NBLK_D 77        // ceil(307/4) blocks per direction
#define SCANB  154       // total scan blocks (2 directions)

// ---------------- helpers ----------------
__device__ __forceinline__ float wsum(float v){
#pragma unroll
  for (int off = 32; off > 0; off >>= 1) v += __shfl_xor(v, off, 64);
  return v;
}
__device__ __forceinline__ float ftanh(float x){
  x = fminf(20.f, fmaxf(-20.f, x));
  float e = __expf(2.f*x);
  return (e - 1.f)/(e + 1.f);
}
__device__ __forceinline__ float fsigm(float x){ return 1.f/(1.f + __expf(-x)); }

// ---------------- prep kernels ----------------
// Sparse rows of Anorm (exact zeros skipped; ascending order keeps fp order)
__global__ void k_sparse(const float* __restrict__ A, int* __restrict__ cnt,
                         int* __restrict__ idx, float* __restrict__ val){
  int n = blockIdx.x*64 + threadIdx.x;
  if (n >= NN) return;
  int c = 0;
  for (int m = 0; m < NN; m++){
    float a = A[n*NN + m];
    if (a != 0.f){ idx[n*NN + c] = m; val[n*NN + c] = a; c++; }
  }
  cnt[n] = c;
}

// W0/W1 (2,4,64,67) -> W0T/W1T [(d*67+i)*256 + p*64+o]
__global__ void k_tr_cheb(const float* __restrict__ W0, const float* __restrict__ W1,
                          float* __restrict__ W0T, float* __restrict__ W1T){
  int t = blockIdx.x*256 + threadIdx.x;
  if (t >= 2*67*256) return;
  int c = t & 255; int rest = t >> 8; int i = rest % 67; int d = rest / 67;
  int p = c >> 6, o = c & 63;
  int src = ((d*4 + p)*64 + o)*67 + i;
  W0T[t] = W0[src];
  W1T[t] = W1[src];
}

// Wih (2,192,66) -> WihT [(d*66+i)*192+j]; Whh (2,192,64) -> WhhT [(d*64+i)*192+j]
__global__ void k_tr_gru(const float* __restrict__ Wih, const float* __restrict__ Whh,
                         float* __restrict__ WihT, float* __restrict__ WhhT){
  int t = blockIdx.x*256 + threadIdx.x;
  if (t < 2*66*192){
    int j = t % 192; int rest = t / 192; int i = rest % 66; int d = rest / 66;
    WihT[t] = Wih[(d*192 + j)*66 + i];
  }
  if (t < 2*64*192){
    int j = t % 192; int rest = t / 192; int i = rest % 64; int d = rest / 64;
    WhhT[t] = Whh[(d*192 + j)*64 + i];
  }
}

// oW (6,64,64) -> oWT [(el*64+i)*64+j]; f2W (6,64,256) -> f2WT [(el*256+i)*64+j]
__global__ void k_tr_enh(const float* __restrict__ oW, const float* __restrict__ f2W,
                         float* __restrict__ oWT, float* __restrict__ f2WT){
  int t = blockIdx.x*256 + threadIdx.x;
  if (t < 6*64*64){
    int j = t & 63; int rest = t >> 6; int i = rest & 63; int el = rest >> 6;
    oWT[t] = oW[(el*64 + j)*64 + i];
  }
  if (t < 6*256*64){
    int j = t & 63; int rest = t >> 6; int i = rest & 255; int el = rest >> 8;
    f2WT[t] = f2W[(el*64 + j)*256 + i];
  }
}

// AF[c][n][t] = sum_m Anorm[n,m]*feat_c[m,t]  (h-independent columns of am)
__global__ void k_af(const float* __restrict__ mseq, const float* __restrict__ tfr,
                     const float* __restrict__ tjm, const int* __restrict__ cnt,
                     const int* __restrict__ idx, const float* __restrict__ val,
                     float* __restrict__ AF){
  int n = blockIdx.x, c = blockIdx.y, t = threadIdx.x;
  const float* feat = (c == 0) ? mseq : (c == 1) ? tfr : tjm;
  float acc = 0.f; int k = cnt[n];
  for (int s = 0; s < k; s++) acc += val[n*NN + s] * feat[idx[n*NN + s]*TT + t];
  AF[((size_t)c*NN + n)*TT + t] = acc;
}

// ---------------- recurrent scan (persistent, 1 grid barrier / step) ----------------
__global__ __launch_bounds__(256, 1)
void k_scan(const float* __restrict__ xseq, const float* __restrict__ mseq,
            const float* __restrict__ tfr, const float* __restrict__ tjm,
            const float* __restrict__ W0T, const float* __restrict__ W1T,
            const float* __restrict__ b0g,
            const float* __restrict__ mixW, const float* __restrict__ mixb,
            const float* __restrict__ WihT, const float* __restrict__ WhhT,
            const float* __restrict__ bih, const float* __restrict__ bhh,
            const float* __restrict__ outW, const float* __restrict__ outb,
            const float* __restrict__ jamW, const float* __restrict__ jamb,
            const int* __restrict__ spcnt, const int* __restrict__ spidx,
            const float* __restrict__ spval, const float* __restrict__ AF,
            float* __restrict__ Hseq, float* __restrict__ PRED, float* __restrict__ JPRED,
            int* __restrict__ slots)
{
  const int tid = threadIdx.x;
  const int bid = blockIdx.x;
  const int d   = bid / NBLK_D;
  const int n0  = (bid % NBLK_D) * 4;
  const int lane = tid & 63;
  const int wid  = tid >> 6;

  __shared__ __align__(16) float hsT[68][4];    // msg_in: rows 0..63 = h, 64..66 = feats
  __shared__ __align__(16) float amsT[68][4];   // am (67 cols)
  __shared__ __align__(16) float msgsT[64][4];
  __shared__ float malls[256][5];
  __shared__ float gis[4][192];
  __shared__ float ghs[4][192];
  __shared__ float mixs[4][4];
  __shared__ float xss[4], mss[4];
  __shared__ int   s_idx[4][320];
  __shared__ float s_val[4][320];
  __shared__ int   s_cnt[4];

  // -------- weight preload into registers (read once, reused 256 steps) --------
  float w0r[67], w1r[67];
#pragma unroll
  for (int i = 0; i < 67; i++){
    w0r[i] = W0T[(d*67 + i)*256 + tid];
    w1r[i] = W1T[(d*67 + i)*256 + tid];
  }
  const float b0r = b0g[d*256 + tid];
  float wih_r[64], whh_r[64];
  float wih64 = 0.f, wih65 = 0.f, bih_r = 0.f, bhh_r = 0.f;
  if (tid < 192){
#pragma unroll
    for (int i = 0; i < 64; i++){
      whh_r[i] = WhhT[(d*64 + i)*192 + tid];
      wih_r[i] = WihT[(d*66 + i)*192 + tid];
    }
    wih64 = WihT[(d*66 + 64)*192 + tid];
    wih65 = WihT[(d*66 + 65)*192 + tid];
    bih_r = bih[d*192 + tid];
    bhh_r = bhh[d*192 + tid];
  }
  float mixw_r[4];
#pragma unroll
  for (int p = 0; p < 4; p++) mixw_r[p] = mixW[(d*4 + p)*64 + lane];
  const float mixb0 = mixb[d*4+0], mixb1 = mixb[d*4+1], mixb2 = mixb[d*4+2], mixb3 = mixb[d*4+3];
  const float outw_r = outW[d*64 + lane], jamw_r = jamW[d*64 + lane];
  const float outb_r = outb[d], jamb_r = jamb[d];

  // -------- sparse neighbor lists into LDS; zero h --------
  for (int r = 0; r < 4; r++){
    const int n = min(n0 + r, NN-1);
    const int cnt = spcnt[n];
    if (tid == 0) s_cnt[r] = cnt;
    for (int s = tid; s < cnt; s += 256){
      s_idx[r][s] = spidx[n*NN + s];
      s_val[r][s] = spval[n*NN + s];
    }
  }
  hsT[lane][wid] = 0.f;
  __syncthreads();

#pragma unroll 1
  for (int k = 0; k < TT; k++){
    const int ts = (d == 0) ? k : (TT-1 - k);
    // phase 0: time-step scalars
    if (tid < 4){
      const int r = tid; const int n = min(n0 + r, NN-1);
      const float mv = mseq[n*TT + ts];
      hsT[64][r] = mv;
      hsT[65][r] = tfr[n*TT + ts];
      hsT[66][r] = tjm[n*TT + ts];
      amsT[64][r] = AF[(0*NN + n)*TT + ts];
      amsT[65][r] = AF[(1*NN + n)*TT + ts];
      amsT[66][r] = AF[(2*NN + n)*TT + ts];
      xss[r] = xseq[n*TT + ts];
      mss[r] = mv;
    }
    // phase 1: am = sparse Anorm @ h_prev (lane = feature, wave = row)
    {
      const float* Hprev = Hseq + (size_t)(d*257 + k)*NN*64;
      const int r = wid;
      const int cnt = s_cnt[r];
      float acc = 0.f;
      int s = 0;
      for (; s + 4 <= cnt; s += 4){
        const int m0 = s_idx[r][s+0], m1 = s_idx[r][s+1], m2 = s_idx[r][s+2], m3 = s_idx[r][s+3];
        const float a0 = s_val[r][s+0], a1 = s_val[r][s+1], a2 = s_val[r][s+2], a3 = s_val[r][s+3];
        const float h0 = Hprev[(size_t)m0*64 + lane];
        const float h1 = Hprev[(size_t)m1*64 + lane];
        const float h2 = Hprev[(size_t)m2*64 + lane];
        const float h3 = Hprev[(size_t)m3*64 + lane];
        acc += a0*h0; acc += a1*h1; acc += a2*h2; acc += a3*h3;
      }
      for (; s < cnt; s++) acc += s_val[r][s] * Hprev[(size_t)s_idx[r][s]*64 + lane];
      amsT[lane][r] = acc;
    }
    // phase 2: mix = softmax(h @ mixW^T + mixb) (wave = row)
    {
      const int r = wid;
      const float hv = hsT[lane][r];
      float l0 = wsum(hv * mixw_r[0]) + mixb0;
      float l1 = wsum(hv * mixw_r[1]) + mixb1;
      float l2 = wsum(hv * mixw_r[2]) + mixb2;
      float l3 = wsum(hv * mixw_r[3]) + mixb3;
      const float mx = fmaxf(fmaxf(l0,l1), fmaxf(l2,l3));
      const float e0 = __expf(l0-mx), e1 = __expf(l1-mx), e2 = __expf(l2-mx), e3 = __expf(l3-mx);
      const float inv = 1.f/(e0+e1+e2+e3);
      if (lane == 0){
        mixs[0][r] = e0*inv; mixs[1][r] = e1*inv; mixs[2][r] = e2*inv; mixs[3][r] = e3*inv;
      }
    }
    __syncthreads();
    // phase 3: m_all = tanh(msg_in@W0^T + am@W1^T + b0), scaled by mix (thread = (p,o))
    {
      const int p = tid >> 6;
      float a0 = b0r, a1 = b0r, a2 = b0r, a3 = b0r;
#pragma unroll
      for (int i = 0; i < 67; i++){
        const float4 h4 = *(const float4*)&hsT[i][0];
        const float4 m4 = *(const float4*)&amsT[i][0];
        const float w0 = w0r[i], w1 = w1r[i];
        a0 += h4.x*w0 + m4.x*w1;
        a1 += h4.y*w0 + m4.y*w1;
        a2 += h4.z*w0 + m4.z*w1;
        a3 += h4.w*w0 + m4.w*w1;
      }
      malls[tid][0] = mixs[p][0]*ftanh(a0);
      malls[tid][1] = mixs[p][1]*ftanh(a1);
      malls[tid][2] = mixs[p][2]*ftanh(a2);
      malls[tid][3] = mixs[p][3]*ftanh(a3);
    }
    __syncthreads();
    // phase 3b: msg = sum_p mix[p]*m_all[p][:]
    msgsT[lane][wid] = malls[lane][wid] + malls[64+lane][wid] + malls[128+lane][wid] + malls[192+lane][wid];
    __syncthreads();
    // phase 4: gi, gh (thread = gate column j)
    if (tid < 192){
      float g0 = bhh_r, g1 = bhh_r, g2 = bhh_r, g3 = bhh_r;
#pragma unroll
      for (int i = 0; i < 64; i++){
        const float4 h4 = *(const float4*)&hsT[i][0];
        const float w = whh_r[i];
        g0 += h4.x*w; g1 += h4.y*w; g2 += h4.z*w; g3 += h4.w*w;
      }
      ghs[0][tid] = g0; ghs[1][tid] = g1; ghs[2][tid] = g2; ghs[3][tid] = g3;
      float q0 = bih_r + (xss[0]*mss[0])*wih64 + mss[0]*wih65;
      float q1 = bih_r + (xss[1]*mss[1])*wih64 + mss[1]*wih65;
      float q2 = bih_r + (xss[2]*mss[2])*wih64 + mss[2]*wih65;
      float q3 = bih_r + (xss[3]*mss[3])*wih64 + mss[3]*wih65;
#pragma unroll
      for (int i = 0; i < 64; i++){
        const float4 m4 = *(const float4*)&msgsT[i][0];
        const float w = wih_r[i];
        q0 += m4.x*w; q1 += m4.y*w; q2 += m4.z*w; q3 += m4.w*w;
      }
      gis[0][tid] = q0; gis[1][tid] = q1; gis[2][tid] = q2; gis[3][tid] = q3;
    }
    __syncthreads();
    // phase 5: GRU update
    {
      const int r = wid, o = lane;
      const float ir = gis[r][o], iz = gis[r][o+64], in_ = gis[r][o+128];
      const float hr = ghs[r][o], hz = ghs[r][o+64], hn = ghs[r][o+128];
      const float rr = fsigm(ir + hr);
      const float zz = fsigm(iz + hz);
      const float nnv = ftanh(in_ + rr*hn);
      const float hold = hsT[o][r];
      const float h2 = (1.f - zz)*nnv + zz*hold + 0.1f*hold;
      hsT[o][r] = h2;
      const int n = n0 + r;
      if (n < NN) Hseq[((size_t)(d*257 + k + 1)*NN + n)*64 + o] = h2;
    }
    __syncthreads();
    // phase 6: pred/jam
    {
      const float h2 = hsT[lane][wid];
      const float pv = wsum(h2 * outw_r);
      const float jv = wsum(h2 * jamw_r);
      const int n = n0 + wid;
      if (lane == 0 && n < NN){
        PRED [(d*NN + n)*TT + ts] = pv + outb_r;
        JPRED[(d*NN + n)*TT + ts] = jv + jamb_r;
      }
    }
    // -------- grid barrier (slot array, release/acquire) --------
    __threadfence();
    __syncthreads();
    if (tid == 0)
      __hip_atomic_store(&slots[bid], k + 1, __ATOMIC_RELEASE, __HIP_MEMORY_SCOPE_AGENT);
    int ok;
    do {
      int mine = 1;
      if (tid < SCANB)
        mine = (__hip_atomic_load(&slots[tid], __ATOMIC_ACQUIRE, __HIP_MEMORY_SCOPE_AGENT) >= k + 1);
      ok = __syncthreads_and(mine);
    } while (!ok);
  }
}

// ---------------- fusion: weights, cell outputs (x0.7), h_fused + pos-enc ----------------
__global__ __launch_bounds__(256)
void k_fusion(const float* __restrict__ PRED, const float* __restrict__ JPRED,
              const float* __restrict__ Hseq,
              const float* __restrict__ fw1, const float* __restrict__ fb1,
              const float* __restrict__ fw2, const float* __restrict__ fb2,
              float* __restrict__ x0, float* __restrict__ outp)
{
  const int tid = threadIdx.x;
  const int rr = tid >> 6, lane = tid & 63;
  const int idx = blockIdx.x*4 + rr;
  const int n = idx >> 8, t = idx & 255;
  const float pf = PRED[(0*NN + n)*TT + t], pb = PRED[(NN + n)*TT + t];
  const float jf = JPRED[(0*NN + n)*TT + t], jb = JPRED[(NN + n)*TT + t];
  const float hid = fmaxf(fw1[lane*2]*pf + fw1[lane*2+1]*pb + fb1[lane], 0.f);
  const float l0 = wsum(hid * fw2[lane]) + fb2[0];
  const float l1 = wsum(hid * fw2[64+lane]) + fb2[1];
  const float mx = fmaxf(l0,l1);
  const float e0 = __expf(l0-mx), e1 = __expf(l1-mx);
  const float inv = 1.f/(e0+e1);
  const float w0 = e0*inv, w1 = e1*inv;
  const float hf = Hseq[((size_t)(0*257 + t + 1)*NN + n)*64 + lane];
  const float hb = Hseq[((size_t)(257 + 256 - t)*NN + n)*64 + lane];
  const int i2 = lane & ~1;
  const float dv = powf(10000.f, (float)i2 * (1.f/64.f));
  const float arg = (float)t / dv;
  const float pe = (lane & 1) ? cosf(arg) : sinf(arg);
  x0[(size_t)idx*64 + lane] = hf*w0 + hb*w1 + pe;
  if (lane == 0){
    outp[idx]        = 0.7f*(w0*pf + w1*pb);
    outp[NROW + idx] = 0.7f*(w0*jf + w1*jb);
  }
}

// ---------------- tiled fp32 GEMM: Y = act(X @ W^T + b), M=NROW, K=64 ----------------
__global__ __launch_bounds__(256)
void k_linear(const float* __restrict__ X, const float* __restrict__ W,
              const float* __restrict__ bias, float* __restrict__ Y,
              int K, int Nout, int act)
{
  __shared__ __align__(16) float Xs[64][68];
  __shared__ __align__(16) float Ws[64][68];
  const int tid = threadIdx.x;
  const int tx = tid & 15, ty = tid >> 4;
  const int brow = blockIdx.x*64, bcol = blockIdx.y*64;
  float acc[4][4] = {};
  for (int k0 = 0; k0 < K; k0 += 64){
    for (int i = tid; i < 64*64; i += 256){
      const int r = i >> 6, c = i & 63;
      Xs[r][c] = X[(size_t)(brow + r)*K + k0 + c];
      Ws[r][c] = W[(size_t)(bcol + r)*K + k0 + c];
    }
    __syncthreads();
#pragma unroll
    for (int kk = 0; kk < 64; kk += 4){
      float4 xv[4], wv[4];
#pragma unroll
      for (int i = 0; i < 4; i++) xv[i] = *(const float4*)&Xs[ty + 16*i][kk];
#pragma unroll
      for (int j = 0; j < 4; j++) wv[j] = *(const float4*)&Ws[tx + 16*j][kk];
#pragma unroll
      for (int i = 0; i < 4; i++)
#pragma unroll
        for (int j = 0; j < 4; j++)
          acc[i][j] += xv[i].x*wv[j].x + xv[i].y*wv[j].y + xv[i].z*wv[j].z + xv[i].w*wv[j].w;
    }
    __syncthreads();
  }
#pragma unroll
  for (int i = 0; i < 4; i++){
    const int gr = brow + ty + 16*i;
#pragma unroll
    for (int j = 0; j < 4; j++){
      const int gc = bcol + tx + 16*j;
      float v = acc[i][j] + bias[gc];
      if (act) v = fmaxf(v, 0.f);
      Y[(size_t)gr*Nout + gc] = v;
    }
  }
}

// ---------------- attention per (node, head): online softmax, thread = q-row ----------------
__global__ __launch_bounds__(256)
void k_attn(const float* __restrict__ QKV, float* __restrict__ O)
{
  const int n = blockIdx.x, h = blockIdx.y;
  const int tid = threadIdx.x;
  __shared__ __align__(16) float Ks[256][16];
  __shared__ __align__(16) float Vs[256][16];
  const float* rowp = QKV + (size_t)n*256*192 + (size_t)tid*192;
  {
    const float4* ks = (const float4*)(rowp + 64 + h*16);
    const float4* vs = (const float4*)(rowp + 128 + h*16);
    float4* kd = (float4*)&Ks[tid][0];
    float4* vd = (float4*)&Vs[tid][0];
    kd[0]=ks[0]; kd[1]=ks[1]; kd[2]=ks[2]; kd[3]=ks[3];
    vd[0]=vs[0]; vd[1]=vs[1]; vd[2]=vs[2]; vd[3]=vs[3];
  }
  float q[16];
  {
    const float4* qs = (const float4*)(rowp + h*16);
#pragma unroll
    for (int c = 0; c < 4; c++){
      float4 t = qs[c];
      q[c*4+0]=t.x*0.25f; q[c*4+1]=t.y*0.25f; q[c*4+2]=t.z*0.25f; q[c*4+3]=t.w*0.25f;
    }
  }
  __syncthreads();
  float m = -1e30f, l = 0.f, acc[16] = {};
  for (int j = 0; j < 256; j++){
    float s = 0.f;
#pragma unroll
    for (int dd = 0; dd < 16; dd++) s += q[dd]*Ks[j][dd];
    const float mn = fmaxf(m, s);
    const float corr = __expf(m - mn);
    const float p = __expf(s - mn);
    l = l*corr + p;
#pragma unroll
    for (int dd = 0; dd < 16; dd++) acc[dd] = acc[dd]*corr + p*Vs[j][dd];
    m = mn;
  }
  const float inv = 1.f/l;
  float* orow = O + ((size_t)n*256 + tid)*64 + h*16;
#pragma unroll
  for (int dd = 0; dd < 16; dd++) orow[dd] = acc[dd]*inv;
}

// ---------------- oproj + residual + LN1 (wave per row, lane = feature) ----------------
__global__ __launch_bounds__(256)
void k_oproj_ln(const float* __restrict__ Xin, const float* __restrict__ Obuf,
                const float* __restrict__ oWT, const float* __restrict__ ob,
                const float* __restrict__ g, const float* __restrict__ b,
                float* __restrict__ Xout)
{
  const int tid = threadIdx.x;
  const int r = tid >> 6, lane = tid & 63;
  const size_t row0 = (size_t)blockIdx.x*4;
  __shared__ float osT[64][4];
  osT[lane][r] = Obuf[(row0 + r)*64 + lane];
  __syncthreads();
  float acc = 0.f;
#pragma unroll 8
  for (int i = 0; i < 64; i++) acc += osT[i][r] * oWT[i*64 + lane];
  float v = Xin[(row0 + r)*64 + lane] + acc + ob[lane];
  const float mu = wsum(v) * (1.f/64.f);
  const float dv = v - mu;
  const float var = wsum(dv*dv) * (1.f/64.f);
  Xout[(row0 + r)*64 + lane] = dv * rsqrtf(var + 1e-5f) * g[lane] + b[lane];
}

// ---------------- FF2 + residual + LN2 (in-place on X) ----------------
__global__ __launch_bounds__(256)
void k_ff2_ln(float* __restrict__ X, const float* __restrict__ F,
              const float* __restrict__ f2WT, const float* __restrict__ f2b,
              const float* __restrict__ g, const float* __restrict__ b)
{
  const int tid = threadIdx.x;
  const int r = tid >> 6, lane = tid & 63;
  const size_t row0 = (size_t)blockIdx.x*4;
  __shared__ float fsT[256][4];
  for (int q = 0; q < 4; q++){
    const int i = (q << 6) | lane;
    fsT[i][r] = F[(row0 + r)*256 + i];
  }
  __syncthreads();
  float acc = 0.f;
#pragma unroll 8
  for (int i = 0; i < 256; i++) acc += fsT[i][r] * f2WT[i*64 + lane];
  float v = X[(row0 + r)*64 + lane] + acc + f2b[lane];
  const float mu = wsum(v) * (1.f/64.f);
  const float dv = v - mu;
  const float var = wsum(dv*dv) * (1.f/64.f);
  X[(row0 + r)*64 + lane] = dv * rsqrtf(var + 1e-5f) * g[lane] + b[lane];
}

// ---------------- final projection, out += 0.3*refined ----------------
__global__ __launch_bounds__(256)
void k_proj_add(const float* __restrict__ X, const float* __restrict__ pW,
                const float* __restrict__ pb, float* __restrict__ outp)
{
  const int tid = threadIdx.x;
  const int r = tid >> 6, lane = tid & 63;
  const size_t row = (size_t)blockIdx.x*4 + r;
  const float v = X[row*64 + lane] * pW[lane];
  const float s = wsum(v);
  if (lane == 0) outp[row] += 0.3f*(s + pb[0]);
}

// ---------------- host launcher ----------------
extern "C" void kernel_launch(void* const* d_in, const int* in_sizes, int n_in,
                              void* d_out, int out_size, void* d_ws, size_t ws_size,
                              hipStream_t stream)
{
  const float* x_seq = (const float*)d_in[0];
  const float* m_seq = (const float*)d_in[1];
  const float* tod_f = (const float*)d_in[2];
  const float* tod_j = (const float*)d_in[3];
  const float* Anorm = (const float*)d_in[4];
  const float* chW0  = (const float*)d_in[5];
  const float* chb0  = (const float*)d_in[6];
  const float* chW1  = (const float*)d_in[7];
  const float* mixW  = (const float*)d_in[8];
  const float* mixb  = (const float*)d_in[9];
  const float* Wih   = (const float*)d_in[10];
  const float* Whh   = (const float*)d_in[11];
  const float* bih   = (const float*)d_in[12];
  const float* bhh   = (const float*)d_in[13];
  const float* outW  = (const float*)d_in[14];
  const float* outbp = (const float*)d_in[15];
  const float* jamW  = (const float*)d_in[16];
  const float* jambp = (const float*)d_in[17];
  const float* fW1   = (const float*)d_in[18];
  const float* fb1   = (const float*)d_in[19];
  const float* fW2   = (const float*)d_in[20];
  const float* fb2   = (const float*)d_in[21];
  const float* qkvW  = (const float*)d_in[22];
  const float* qkvb  = (const float*)d_in[23];
  const float* oW    = (const float*)d_in[24];
  const float* ob    = (const float*)d_in[25];
  const float* ln1g  = (const float*)d_in[26];
  const float* ln1b  = (const float*)d_in[27];
  const float* f1W   = (const float*)d_in[28];
  const float* f1b   = (const float*)d_in[29];
  const float* f2W   = (const float*)d_in[30];
  const float* f2b   = (const float*)d_in[31];
  const float* ln2g  = (const float*)d_in[32];
  const float* ln2b  = (const float*)d_in[33];
  const float* prW   = (const float*)d_in[34];
  const float* prb   = (const float*)d_in[35];
  float* out = (float*)d_out;

  // workspace layout (needs ~186 MB)
  float* ws = (float*)d_ws;
  size_t off = 0;
  auto take = [&](size_t n)->float*{ float* p = ws + off; off += (n + 63) & ~(size_t)63; return p; };
  int*   slots = (int*)take(256);
  float* W0T  = take((size_t)2*67*256);
  float* W1T  = take((size_t)2*67*256);
  float* WihT = take((size_t)2*66*192);
  float* WhhT = take((size_t)2*64*192);
  float* oWT  = take((size_t)6*64*64);
  float* f2WT = take((size_t)6*256*64);
  int*   spcnt = (int*)take(320);
  int*   spidx = (int*)take((size_t)NN*NN);
  float* spval = take((size_t)NN*NN);
  float* AF    = take((size_t)3*NN*TT);
  float* PRED  = take((size_t)2*NN*TT);
  float* JPRED = take((size_t)2*NN*TT);
  float* HSEQ  = take((size_t)2*257*NN*64);
  float* X0    = take((size_t)NROW*64);
  float* XBUF  = take((size_t)NROW*64);
  float* OBUF  = take((size_t)NROW*64);
  float* FBUF  = take((size_t)NROW*256);   // also holds QKV (192-stride)
  (void)ws_size; (void)in_sizes; (void)n_in; (void)out_size;

  hipMemsetAsync(slots, 0, 256*sizeof(int), stream);
  hipMemsetAsync(HSEQ, 0, (size_t)NN*64*sizeof(float), stream);                    // h0 fwd
  hipMemsetAsync(HSEQ + (size_t)257*NN*64, 0, (size_t)NN*64*sizeof(float), stream); // h0 bwd

  k_sparse<<<dim3((NN+63)/64), dim3(64), 0, stream>>>(Anorm, spcnt, spidx, spval);
  k_tr_cheb<<<dim3(134), dim3(256), 0, stream>>>(chW0, chW1, W0T, W1T);
  k_tr_gru<<<dim3(99), dim3(256), 0, stream>>>(Wih, Whh, WihT, WhhT);
  k_tr_enh<<<dim3(384), dim3(256), 0, stream>>>(oW, f2W, oWT, f2WT);
  k_af<<<dim3(NN,3), dim3(256), 0, stream>>>(m_seq, tod_f, tod_j, spcnt, spidx, spval, AF);

  k_scan<<<dim3(SCANB), dim3(256), 0, stream>>>(x_seq, m_seq, tod_f, tod_j, W0T, W1T,
      chb0, mixW, mixb, WihT, WhhT, bih, bhh, outW, outbp, jamW, jambp,
      spcnt, spidx, spval, AF, HSEQ, PRED, JPRED, slots);

  k_fusion<<<dim3(NROW/4), dim3(256), 0, stream>>>(PRED, JPRED, HSEQ, fW1, fb1, fW2, fb2, X0, out);

  for (int e = 0; e < 2; e++){
    for (int l = 0; l < 3; l++){
      const int el = e*3 + l;
      const float* xin = (l == 0) ? X0 : XBUF;
      k_linear<<<dim3(NROW/64, 3), dim3(256), 0, stream>>>(xin, qkvW + (size_t)el*192*64,
          qkvb + (size_t)el*192, FBUF, 64, 192, 0);
      k_attn<<<dim3(NN, 4), dim3(256), 0, stream>>>(FBUF, OBUF);
      k_oproj_ln<<<dim3(NROW/4), dim3(256), 0, stream>>>(xin, OBUF, oWT + (size_t)el*64*64,
          ob + (size_t)el*64, ln1g + (size_t)el*64, ln1b + (size_t)el*64, XBUF);
      k_linear<<<dim3(NROW/64, 4), dim3(256), 0, stream>>>(XBUF, f1W + (size_t)el*256*64,
          f1b + (size_t)el*256, FBUF, 64, 256, 1);
      k_ff2_ln<<<dim3(NROW/4), dim3(256), 0, stream>>>(XBUF, FBUF, f2WT + (size_t)el*256*64,
          f2b + (size_t)el*64, ln2g + (size_t)el*64, ln2b + (size_t)el*64);
    }
    k_proj_add<<<dim3(NROW/4), dim3(256), 0, stream>>>(XBUF, prW + (size_t)e*64, prb + e,
        out + (size_t)e*NROW);
  }
}

// Round 2
// 8581.080 us; speedup vs baseline: 1.2861x; 1.2861x over previous
//
#include <hip/hip_runtime.h>
#include <math.h>

// Problem constants
#define NN   307
#define TT   256
#define HHH  64
#define NROW (NN*TT)     // 78592
#define NBLK_D 77        // ceil(307/4) blocks per direction
#define SCANB  154       // total scan blocks (2 directions)

// ---------------- helpers ----------------
__device__ __forceinline__ float wsum(float v){
#pragma unroll
  for (int off = 32; off > 0; off >>= 1) v += __shfl_xor(v, off, 64);
  return v;
}
__device__ __forceinline__ float ftanh(float x){
  x = fminf(20.f, fmaxf(-20.f, x));
  float e = __expf(2.f*x);
  return (e - 1.f)/(e + 1.f);
}
__device__ __forceinline__ float fsigm(float x){ return 1.f/(1.f + __expf(-x)); }

// ---------------- prep kernels ----------------
__global__ void k_sparse(const float* __restrict__ A, int* __restrict__ cnt,
                         int* __restrict__ idx, float* __restrict__ val){
  int n = blockIdx.x*64 + threadIdx.x;
  if (n >= NN) return;
  int c = 0;
  for (int m = 0; m < NN; m++){
    float a = A[n*NN + m];
    if (a != 0.f){ idx[n*NN + c] = m; val[n*NN + c] = a; c++; }
  }
  cnt[n] = c;
}

__global__ void k_tr_cheb(const float* __restrict__ W0, const float* __restrict__ W1,
                          float* __restrict__ W0T, float* __restrict__ W1T){
  int t = blockIdx.x*256 + threadIdx.x;
  if (t >= 2*67*256) return;
  int c = t & 255; int rest = t >> 8; int i = rest % 67; int d = rest / 67;
  int p = c >> 6, o = c & 63;
  int src = ((d*4 + p)*64 + o)*67 + i;
  W0T[t] = W0[src];
  W1T[t] = W1[src];
}

__global__ void k_tr_gru(const float* __restrict__ Wih, const float* __restrict__ Whh,
                         float* __restrict__ WihT, float* __restrict__ WhhT){
  int t = blockIdx.x*256 + threadIdx.x;
  if (t < 2*66*192){
    int j = t % 192; int rest = t / 192; int i = rest % 66; int d = rest / 66;
    WihT[t] = Wih[(d*192 + j)*66 + i];
  }
  if (t < 2*64*192){
    int j = t % 192; int rest = t / 192; int i = rest % 64; int d = rest / 64;
    WhhT[t] = Whh[(d*192 + j)*64 + i];
  }
}

__global__ void k_tr_enh(const float* __restrict__ oW, const float* __restrict__ f2W,
                         float* __restrict__ oWT, float* __restrict__ f2WT){
  int t = blockIdx.x*256 + threadIdx.x;
  if (t < 6*64*64){
    int j = t & 63; int rest = t >> 6; int i = rest & 63; int el = rest >> 6;
    oWT[t] = oW[(el*64 + j)*64 + i];
  }
  if (t < 6*256*64){
    int j = t & 63; int rest = t >> 6; int i = rest & 255; int el = rest >> 8;
    f2WT[t] = f2W[(el*64 + j)*256 + i];
  }
}

__global__ void k_af(const float* __restrict__ mseq, const float* __restrict__ tfr,
                     const float* __restrict__ tjm, const int* __restrict__ cnt,
                     const int* __restrict__ idx, const float* __restrict__ val,
                     float* __restrict__ AF){
  int n = blockIdx.x, c = blockIdx.y, t = threadIdx.x;
  const float* feat = (c == 0) ? mseq : (c == 1) ? tfr : tjm;
  float acc = 0.f; int k = cnt[n];
  for (int s = 0; s < k; s++) acc += val[n*NN + s] * feat[idx[n*NN + s]*TT + t];
  AF[((size_t)c*NN + n)*TT + t] = acc;
}

// ---------------- recurrent scan (persistent, counter+gen barrier per direction) ----
__global__ __launch_bounds__(256, 1)
void k_scan(const float* __restrict__ xseq, const float* __restrict__ mseq,
            const float* __restrict__ tfr, const float* __restrict__ tjm,
            const float* __restrict__ W0T, const float* __restrict__ W1T,
            const float* __restrict__ b0g,
            const float* __restrict__ mixW, const float* __restrict__ mixb,
            const float* __restrict__ WihT, const float* __restrict__ WhhT,
            const float* __restrict__ bih, const float* __restrict__ bhh,
            const float* __restrict__ outW, const float* __restrict__ outb,
            const float* __restrict__ jamW, const float* __restrict__ jamb,
            const int* __restrict__ spcnt, const int* __restrict__ spidx,
            const float* __restrict__ spval, const float* __restrict__ AF,
            float* __restrict__ Hseq, float* __restrict__ PRED, float* __restrict__ JPRED,
            int* __restrict__ bar)   // bar[0..1]=arrive cnt per dir, bar[16..17]=gen per dir
{
  const int tid = threadIdx.x;
  const int bid = blockIdx.x;
  const int d   = bid / NBLK_D;
  const int n0  = (bid % NBLK_D) * 4;
  const int lane = tid & 63;
  const int wid  = tid >> 6;

  int* cnt_p = bar + d;        // arrive counter (monotonic)
  int* gen_p = bar + 16 + d;   // generation word (monotonic)

  __shared__ __align__(16) float hsT[68][4];    // msg_in: rows 0..63 = h, 64..66 = feats
  __shared__ __align__(16) float amsT[68][4];   // am (67 cols)
  __shared__ __align__(16) float msgsT[64][4];
  __shared__ float malls[256][5];
  __shared__ float gis[4][192];
  __shared__ float ghs[4][192];
  __shared__ float mixs[4][4];
  __shared__ float xss[4], mss[4];
  __shared__ int   s_idx[4][320];
  __shared__ float s_val[4][320];
  __shared__ int   s_cnt[4];

  // -------- weight preload into registers (read once, reused 256 steps) --------
  float w0r[67], w1r[67];
#pragma unroll
  for (int i = 0; i < 67; i++){
    w0r[i] = W0T[(d*67 + i)*256 + tid];
    w1r[i] = W1T[(d*67 + i)*256 + tid];
  }
  const float b0r = b0g[d*256 + tid];
  float wih_r[64], whh_r[64];
  float wih64 = 0.f, wih65 = 0.f, bih_r = 0.f, bhh_r = 0.f;
  if (tid < 192){
#pragma unroll
    for (int i = 0; i < 64; i++){
      whh_r[i] = WhhT[(d*64 + i)*192 + tid];
      wih_r[i] = WihT[(d*66 + i)*192 + tid];
    }
    wih64 = WihT[(d*66 + 64)*192 + tid];
    wih65 = WihT[(d*66 + 65)*192 + tid];
    bih_r = bih[d*192 + tid];
    bhh_r = bhh[d*192 + tid];
  }
  float mixw_r[4];
#pragma unroll
  for (int p = 0; p < 4; p++) mixw_r[p] = mixW[(d*4 + p)*64 + lane];
  const float mixb0 = mixb[d*4+0], mixb1 = mixb[d*4+1], mixb2 = mixb[d*4+2], mixb3 = mixb[d*4+3];
  const float outw_r = outW[d*64 + lane], jamw_r = jamW[d*64 + lane];
  const float outb_r = outb[d], jamb_r = jamb[d];

  // -------- sparse neighbor lists into LDS; zero h --------
  for (int r = 0; r < 4; r++){
    const int n = min(n0 + r, NN-1);
    const int cc = spcnt[n];
    if (tid == 0) s_cnt[r] = cc;
    for (int s = tid; s < cc; s += 256){
      s_idx[r][s] = spidx[n*NN + s];
      s_val[r][s] = spval[n*NN + s];
    }
  }
  hsT[lane][wid] = 0.f;
  __syncthreads();

#pragma unroll 1
  for (int k = 0; k < TT; k++){
    const int ts = (d == 0) ? k : (TT-1 - k);
    // phase 0: time-step scalars
    if (tid < 4){
      const int r = tid; const int n = min(n0 + r, NN-1);
      const float mv = mseq[n*TT + ts];
      hsT[64][r] = mv;
      hsT[65][r] = tfr[n*TT + ts];
      hsT[66][r] = tjm[n*TT + ts];
      amsT[64][r] = AF[(0*NN + n)*TT + ts];
      amsT[65][r] = AF[(1*NN + n)*TT + ts];
      amsT[66][r] = AF[(2*NN + n)*TT + ts];
      xss[r] = xseq[n*TT + ts];
      mss[r] = mv;
    }
    // phase 1: am = sparse Anorm @ h_prev (lane = feature, wave = row)
    {
      const float* Hprev = Hseq + (size_t)(d*257 + k)*NN*64;
      const int r = wid;
      const int cc = s_cnt[r];
      float acc = 0.f;
      int s = 0;
      for (; s + 4 <= cc; s += 4){
        const int m0 = s_idx[r][s+0], m1 = s_idx[r][s+1], m2 = s_idx[r][s+2], m3 = s_idx[r][s+3];
        const float a0 = s_val[r][s+0], a1 = s_val[r][s+1], a2 = s_val[r][s+2], a3 = s_val[r][s+3];
        const float h0 = Hprev[(size_t)m0*64 + lane];
        const float h1 = Hprev[(size_t)m1*64 + lane];
        const float h2 = Hprev[(size_t)m2*64 + lane];
        const float h3 = Hprev[(size_t)m3*64 + lane];
        acc += a0*h0; acc += a1*h1; acc += a2*h2; acc += a3*h3;
      }
      for (; s < cc; s++) acc += s_val[r][s] * Hprev[(size_t)s_idx[r][s]*64 + lane];
      amsT[lane][r] = acc;
    }
    // phase 2: mix = softmax(h @ mixW^T + mixb)
    {
      const int r = wid;
      const float hv = hsT[lane][r];
      float l0 = wsum(hv * mixw_r[0]) + mixb0;
      float l1 = wsum(hv * mixw_r[1]) + mixb1;
      float l2 = wsum(hv * mixw_r[2]) + mixb2;
      float l3 = wsum(hv * mixw_r[3]) + mixb3;
      const float mx = fmaxf(fmaxf(l0,l1), fmaxf(l2,l3));
      const float e0 = __expf(l0-mx), e1 = __expf(l1-mx), e2 = __expf(l2-mx), e3 = __expf(l3-mx);
      const float inv = 1.f/(e0+e1+e2+e3);
      if (lane == 0){
        mixs[0][r] = e0*inv; mixs[1][r] = e1*inv; mixs[2][r] = e2*inv; mixs[3][r] = e3*inv;
      }
    }
    __syncthreads();
    // phase 3: m_all = tanh(msg_in@W0^T + am@W1^T + b0), scaled by mix
    {
      const int p = tid >> 6;
      float a0 = b0r, a1 = b0r, a2 = b0r, a3 = b0r;
#pragma unroll
      for (int i = 0; i < 67; i++){
        const float4 h4 = *(const float4*)&hsT[i][0];
        const float4 m4 = *(const float4*)&amsT[i][0];
        const float w0 = w0r[i], w1 = w1r[i];
        a0 += h4.x*w0 + m4.x*w1;
        a1 += h4.y*w0 + m4.y*w1;
        a2 += h4.z*w0 + m4.z*w1;
        a3 += h4.w*w0 + m4.w*w1;
      }
      malls[tid][0] = mixs[p][0]*ftanh(a0);
      malls[tid][1] = mixs[p][1]*ftanh(a1);
      malls[tid][2] = mixs[p][2]*ftanh(a2);
      malls[tid][3] = mixs[p][3]*ftanh(a3);
    }
    __syncthreads();
    // phase 3b: msg = sum_p m_all[p][:]
    msgsT[lane][wid] = malls[lane][wid] + malls[64+lane][wid] + malls[128+lane][wid] + malls[192+lane][wid];
    __syncthreads();
    // phase 4: gi, gh (thread = gate column j)
    if (tid < 192){
      float g0 = bhh_r, g1 = bhh_r, g2 = bhh_r, g3 = bhh_r;
#pragma unroll
      for (int i = 0; i < 64; i++){
        const float4 h4 = *(const float4*)&hsT[i][0];
        const float w = whh_r[i];
        g0 += h4.x*w; g1 += h4.y*w; g2 += h4.z*w; g3 += h4.w*w;
      }
      ghs[0][tid] = g0; ghs[1][tid] = g1; ghs[2][tid] = g2; ghs[3][tid] = g3;
      float q0 = bih_r + (xss[0]*mss[0])*wih64 + mss[0]*wih65;
      float q1 = bih_r + (xss[1]*mss[1])*wih64 + mss[1]*wih65;
      float q2 = bih_r + (xss[2]*mss[2])*wih64 + mss[2]*wih65;
      float q3 = bih_r + (xss[3]*mss[3])*wih64 + mss[3]*wih65;
#pragma unroll
      for (int i = 0; i < 64; i++){
        const float4 m4 = *(const float4*)&msgsT[i][0];
        const float w = wih_r[i];
        q0 += m4.x*w; q1 += m4.y*w; q2 += m4.z*w; q3 += m4.w*w;
      }
      gis[0][tid] = q0; gis[1][tid] = q1; gis[2][tid] = q2; gis[3][tid] = q3;
    }
    __syncthreads();
    // phase 5: GRU update + h write
    {
      const int r = wid, o = lane;
      const float ir = gis[r][o], iz = gis[r][o+64], in_ = gis[r][o+128];
      const float hr = ghs[r][o], hz = ghs[r][o+64], hn = ghs[r][o+128];
      const float rr = fsigm(ir + hr);
      const float zz = fsigm(iz + hz);
      const float nnv = ftanh(in_ + rr*hn);
      const float hold = hsT[o][r];
      const float h2 = (1.f - zz)*nnv + zz*hold + 0.1f*hold;
      hsT[o][r] = h2;
      const int n = n0 + r;
      if (n < NN) Hseq[((size_t)(d*257 + k + 1)*NN + n)*64 + o] = h2;
    }
    __syncthreads();   // drains all waves' Hseq stores (vmcnt(0) before s_barrier)
    // phase 6: pred/jam (no cross-block consumer until after kernel end)
    {
      const float h2 = hsT[lane][wid];
      const float pv = wsum(h2 * outw_r);
      const float jv = wsum(h2 * jamw_r);
      const int n = n0 + wid;
      if (lane == 0 && n < NN){
        PRED [(d*NN + n)*TT + ts] = pv + outb_r;
        JPRED[(d*NN + n)*TT + ts] = jv + jamb_r;
      }
    }
    // -------- grid barrier: counter + generation, per direction, tid0 only ------
    if (tid == 0){
      __threadfence();   // release: writeback this CU/XCD's dirty lines once
      const int prev = __hip_atomic_fetch_add(cnt_p, 1, __ATOMIC_RELAXED,
                                              __HIP_MEMORY_SCOPE_AGENT);
      if (prev == NBLK_D*(k+1) - 1){
        __hip_atomic_store(gen_p, k+1, __ATOMIC_RELAXED, __HIP_MEMORY_SCOPE_AGENT);
      } else {
        while (__hip_atomic_load(gen_p, __ATOMIC_RELAXED,
                                 __HIP_MEMORY_SCOPE_AGENT) < k+1)
          __builtin_amdgcn_s_sleep(1);
      }
      __builtin_amdgcn_fence(__ATOMIC_ACQUIRE, "agent");  // single invalidate
    }
    __syncthreads();
  }
}

// ---------------- fusion: weights, cell outputs (x0.7), h_fused + pos-enc ----------------
__global__ __launch_bounds__(256)
void k_fusion(const float* __restrict__ PRED, const float* __restrict__ JPRED,
              const float* __restrict__ Hseq,
              const float* __restrict__ fw1, const float* __restrict__ fb1,
              const float* __restrict__ fw2, const float* __restrict__ fb2,
              float* __restrict__ x0, float* __restrict__ outp)
{
  const int tid = threadIdx.x;
  const int rr = tid >> 6, lane = tid & 63;
  const int idx = blockIdx.x*4 + rr;
  const int n = idx >> 8, t = idx & 255;
  const float pf = PRED[(0*NN + n)*TT + t], pb = PRED[(NN + n)*TT + t];
  const float jf = JPRED[(0*NN + n)*TT + t], jb = JPRED[(NN + n)*TT + t];
  const float hid = fmaxf(fw1[lane*2]*pf + fw1[lane*2+1]*pb + fb1[lane], 0.f);
  const float l0 = wsum(hid * fw2[lane]) + fb2[0];
  const float l1 = wsum(hid * fw2[64+lane]) + fb2[1];
  const float mx = fmaxf(l0,l1);
  const float e0 = __expf(l0-mx), e1 = __expf(l1-mx);
  const float inv = 1.f/(e0+e1);
  const float w0 = e0*inv, w1 = e1*inv;
  const float hf = Hseq[((size_t)(0*257 + t + 1)*NN + n)*64 + lane];
  const float hb = Hseq[((size_t)(257 + 256 - t)*NN + n)*64 + lane];
  const int i2 = lane & ~1;
  const float dv = powf(10000.f, (float)i2 * (1.f/64.f));
  const float arg = (float)t / dv;
  const float pe = (lane & 1) ? cosf(arg) : sinf(arg);
  x0[(size_t)idx*64 + lane] = hf*w0 + hb*w1 + pe;
  if (lane == 0){
    outp[idx]        = 0.7f*(w0*pf + w1*pb);
    outp[NROW + idx] = 0.7f*(w0*jf + w1*jb);
  }
}

// ---------------- tiled fp32 GEMM: Y = act(X @ W^T + b), M=NROW, K=64 ----------------
__global__ __launch_bounds__(256)
void k_linear(const float* __restrict__ X, const float* __restrict__ W,
              const float* __restrict__ bias, float* __restrict__ Y,
              int K, int Nout, int act)
{
  __shared__ __align__(16) float Xs[64][68];
  __shared__ __align__(16) float Ws[64][68];
  const int tid = threadIdx.x;
  const int tx = tid & 15, ty = tid >> 4;
  const int brow = blockIdx.x*64, bcol = blockIdx.y*64;
  float acc[4][4] = {};
  for (int k0 = 0; k0 < K; k0 += 64){
    for (int i = tid; i < 64*64; i += 256){
      const int r = i >> 6, c = i & 63;
      Xs[r][c] = X[(size_t)(brow + r)*K + k0 + c];
      Ws[r][c] = W[(size_t)(bcol + r)*K + k0 + c];
    }
    __syncthreads();
#pragma unroll
    for (int kk = 0; kk < 64; kk += 4){
      float4 xv[4], wv[4];
#pragma unroll
      for (int i = 0; i < 4; i++) xv[i] = *(const float4*)&Xs[ty + 16*i][kk];
#pragma unroll
      for (int j = 0; j < 4; j++) wv[j] = *(const float4*)&Ws[tx + 16*j][kk];
#pragma unroll
      for (int i = 0; i < 4; i++)
#pragma unroll
        for (int j = 0; j < 4; j++)
          acc[i][j] += xv[i].x*wv[j].x + xv[i].y*wv[j].y + xv[i].z*wv[j].z + xv[i].w*wv[j].w;
    }
    __syncthreads();
  }
#pragma unroll
  for (int i = 0; i < 4; i++){
    const int gr = brow + ty + 16*i;
#pragma unroll
    for (int j = 0; j < 4; j++){
      const int gc = bcol + tx + 16*j;
      float v = acc[i][j] + bias[gc];
      if (act) v = fmaxf(v, 0.f);
      Y[(size_t)gr*Nout + gc] = v;
    }
  }
}

// ---------------- attention per (node, head): online softmax, thread = q-row ----------------
__global__ __launch_bounds__(256)
void k_attn(const float* __restrict__ QKV, float* __restrict__ O)
{
  const int n = blockIdx.x, h = blockIdx.y;
  const int tid = threadIdx.x;
  __shared__ __align__(16) float Ks[256][16];
  __shared__ __align__(16) float Vs[256][16];
  const float* rowp = QKV + (size_t)n*256*192 + (size_t)tid*192;
  {
    const float4* ks = (const float4*)(rowp + 64 + h*16);
    const float4* vs = (const float4*)(rowp + 128 + h*16);
    float4* kd = (float4*)&Ks[tid][0];
    float4* vd = (float4*)&Vs[tid][0];
    kd[0]=ks[0]; kd[1]=ks[1]; kd[2]=ks[2]; kd[3]=ks[3];
    vd[0]=vs[0]; vd[1]=vs[1]; vd[2]=vs[2]; vd[3]=vs[3];
  }
  float q[16];
  {
    const float4* qs = (const float4*)(rowp + h*16);
#pragma unroll
    for (int c = 0; c < 4; c++){
      float4 t = qs[c];
      q[c*4+0]=t.x*0.25f; q[c*4+1]=t.y*0.25f; q[c*4+2]=t.z*0.25f; q[c*4+3]=t.w*0.25f;
    }
  }
  __syncthreads();
  float m = -1e30f, l = 0.f, acc[16] = {};
  for (int j = 0; j < 256; j++){
    float s = 0.f;
#pragma unroll
    for (int dd = 0; dd < 16; dd++) s += q[dd]*Ks[j][dd];
    const float mn = fmaxf(m, s);
    const float corr = __expf(m - mn);
    const float p = __expf(s - mn);
    l = l*corr + p;
#pragma unroll
    for (int dd = 0; dd < 16; dd++) acc[dd] = acc[dd]*corr + p*Vs[j][dd];
    m = mn;
  }
  const float inv = 1.f/l;
  float* orow = O + ((size_t)n*256 + tid)*64 + h*16;
#pragma unroll
  for (int dd = 0; dd < 16; dd++) orow[dd] = acc[dd]*inv;
}

// ---------------- oproj + residual + LN1 (wave per row, lane = feature) ----------------
__global__ __launch_bounds__(256)
void k_oproj_ln(const float* __restrict__ Xin, const float* __restrict__ Obuf,
                const float* __restrict__ oWT, const float* __restrict__ ob,
                const float* __restrict__ g, const float* __restrict__ b,
                float* __restrict__ Xout)
{
  const int tid = threadIdx.x;
  const int r = tid >> 6, lane = tid & 63;
  const size_t row0 = (size_t)blockIdx.x*4;
  __shared__ float osT[64][4];
  osT[lane][r] = Obuf[(row0 + r)*64 + lane];
  __syncthreads();
  float acc = 0.f;
#pragma unroll 8
  for (int i = 0; i < 64; i++) acc += osT[i][r] * oWT[i*64 + lane];
  float v = Xin[(row0 + r)*64 + lane] + acc + ob[lane];
  const float mu = wsum(v) * (1.f/64.f);
  const float dv = v - mu;
  const float var = wsum(dv*dv) * (1.f/64.f);
  Xout[(row0 + r)*64 + lane] = dv * rsqrtf(var + 1e-5f) * g[lane] + b[lane];
}

// ---------------- FF2 + residual + LN2 (in-place on X) ----------------
__global__ __launch_bounds__(256)
void k_ff2_ln(float* __restrict__ X, const float* __restrict__ F,
              const float* __restrict__ f2WT, const float* __restrict__ f2b,
              const float* __restrict__ g, const float* __restrict__ b)
{
  const int tid = threadIdx.x;
  const int r = tid >> 6, lane = tid & 63;
  const size_t row0 = (size_t)blockIdx.x*4;
  __shared__ float fsT[256][4];
  for (int q = 0; q < 4; q++){
    const int i = (q << 6) | lane;
    fsT[i][r] = F[(row0 + r)*256 + i];
  }
  __syncthreads();
  float acc = 0.f;
#pragma unroll 8
  for (int i = 0; i < 256; i++) acc += fsT[i][r] * f2WT[i*64 + lane];
  float v = X[(row0 + r)*64 + lane] + acc + f2b[lane];
  const float mu = wsum(v) * (1.f/64.f);
  const float dv = v - mu;
  const float var = wsum(dv*dv) * (1.f/64.f);
  X[(row0 + r)*64 + lane] = dv * rsqrtf(var + 1e-5f) * g[lane] + b[lane];
}

// ---------------- final projection, out += 0.3*refined ----------------
__global__ __launch_bounds__(256)
void k_proj_add(const float* __restrict__ X, const float* __restrict__ pW,
                const float* __restrict__ pb, float* __restrict__ outp)
{
  const int tid = threadIdx.x;
  const int r = tid >> 6, lane = tid & 63;
  const size_t row = (size_t)blockIdx.x*4 + r;
  const float v = X[row*64 + lane] * pW[lane];
  const float s = wsum(v);
  if (lane == 0) outp[row] += 0.3f*(s + pb[0]);
}

// ---------------- host launcher ----------------
extern "C" void kernel_launch(void* const* d_in, const int* in_sizes, int n_in,
                              void* d_out, int out_size, void* d_ws, size_t ws_size,
                              hipStream_t stream)
{
  const float* x_seq = (const float*)d_in[0];
  const float* m_seq = (const float*)d_in[1];
  const float* tod_f = (const float*)d_in[2];
  const float* tod_j = (const float*)d_in[3];
  const float* Anorm = (const float*)d_in[4];
  const float* chW0  = (const float*)d_in[5];
  const float* chb0  = (const float*)d_in[6];
  const float* chW1  = (const float*)d_in[7];
  const float* mixW  = (const float*)d_in[8];
  const float* mixb  = (const float*)d_in[9];
  const float* Wih   = (const float*)d_in[10];
  const float* Whh   = (const float*)d_in[11];
  const float* bih   = (const float*)d_in[12];
  const float* bhh   = (const float*)d_in[13];
  const float* outW  = (const float*)d_in[14];
  const float* outbp = (const float*)d_in[15];
  const float* jamW  = (const float*)d_in[16];
  const float* jambp = (const float*)d_in[17];
  const float* fW1   = (const float*)d_in[18];
  const float* fb1   = (const float*)d_in[19];
  const float* fW2   = (const float*)d_in[20];
  const float* fb2   = (const float*)d_in[21];
  const float* qkvW  = (const float*)d_in[22];
  const float* qkvb  = (const float*)d_in[23];
  const float* oW    = (const float*)d_in[24];
  const float* ob    = (const float*)d_in[25];
  const float* ln1g  = (const float*)d_in[26];
  const float* ln1b  = (const float*)d_in[27];
  const float* f1W   = (const float*)d_in[28];
  const float* f1b   = (const float*)d_in[29];
  const float* f2W   = (const float*)d_in[30];
  const float* f2b   = (const float*)d_in[31];
  const float* ln2g  = (const float*)d_in[32];
  const float* ln2b  = (const float*)d_in[33];
  const float* prW   = (const float*)d_in[34];
  const float* prb   = (const float*)d_in[35];
  float* out = (float*)d_out;

  float* ws = (float*)d_ws;
  size_t off = 0;
  auto take = [&](size_t n)->float*{ float* p = ws + off; off += (n + 63) & ~(size_t)63; return p; };
  int*   bar  = (int*)take(256);
  float* W0T  = take((size_t)2*67*256);
  float* W1T  = take((size_t)2*67*256);
  float* WihT = take((size_t)2*66*192);
  float* WhhT = take((size_t)2*64*192);
  float* oWT  = take((size_t)6*64*64);
  float* f2WT = take((size_t)6*256*64);
  int*   spcnt = (int*)take(320);
  int*   spidx = (int*)take((size_t)NN*NN);
  float* spval = take((size_t)NN*NN);
  float* AF    = take((size_t)3*NN*TT);
  float* PRED  = take((size_t)2*NN*TT);
  float* JPRED = take((size_t)2*NN*TT);
  float* HSEQ  = take((size_t)2*257*NN*64);
  float* X0    = take((size_t)NROW*64);
  float* XBUF  = take((size_t)NROW*64);
  float* OBUF  = take((size_t)NROW*64);
  float* FBUF  = take((size_t)NROW*256);   // also holds QKV (192-stride)
  (void)ws_size; (void)in_sizes; (void)n_in; (void)out_size;

  hipMemsetAsync(bar, 0, 256*sizeof(int), stream);
  hipMemsetAsync(HSEQ, 0, (size_t)NN*64*sizeof(float), stream);                     // h0 fwd
  hipMemsetAsync(HSEQ + (size_t)257*NN*64, 0, (size_t)NN*64*sizeof(float), stream); // h0 bwd

  k_sparse<<<dim3((NN+63)/64), dim3(64), 0, stream>>>(Anorm, spcnt, spidx, spval);
  k_tr_cheb<<<dim3(134), dim3(256), 0, stream>>>(chW0, chW1, W0T, W1T);
  k_tr_gru<<<dim3(99), dim3(256), 0, stream>>>(Wih, Whh, WihT, WhhT);
  k_tr_enh<<<dim3(384), dim3(256), 0, stream>>>(oW, f2W, oWT, f2WT);
  k_af<<<dim3(NN,3), dim3(256), 0, stream>>>(m_seq, tod_f, tod_j, spcnt, spidx, spval, AF);

  k_scan<<<dim3(SCANB), dim3(256), 0, stream>>>(x_seq, m_seq, tod_f, tod_j, W0T, W1T,
      chb0, mixW, mixb, WihT, WhhT, bih, bhh, outW, outbp, jamW, jambp,
      spcnt, spidx, spval, AF, HSEQ, PRED, JPRED, bar);

  k_fusion<<<dim3(NROW/4), dim3(256), 0, stream>>>(PRED, JPRED, HSEQ, fW1, fb1, fW2, fb2, X0, out);

  for (int e = 0; e < 2; e++){
    for (int l = 0; l < 3; l++){
      const int el = e*3 + l;
      const float* xin = (l == 0) ? X0 : XBUF;
      k_linear<<<dim3(NROW/64, 3), dim3(256), 0, stream>>>(xin, qkvW + (size_t)el*192*64,
          qkvb + (size_t)el*192, FBUF, 64, 192, 0);
      k_attn<<<dim3(NN, 4), dim3(256), 0, stream>>>(FBUF, OBUF);
      k_oproj_ln<<<dim3(NROW/4), dim3(256), 0, stream>>>(xin, OBUF, oWT + (size_t)el*64*64,
          ob + (size_t)el*64, ln1g + (size_t)el*64, ln1b + (size_t)el*64, XBUF);
      k_linear<<<dim3(NROW/64, 4), dim3(256), 0, stream>>>(XBUF, f1W + (size_t)el*256*64,
          f1b + (size_t)el*256, FBUF, 64, 256, 1);
      k_ff2_ln<<<dim3(NROW/4), dim3(256), 0, stream>>>(XBUF, FBUF, f2WT + (size_t)el*256*64,
          f2b + (size_t)el*64, ln2g + (size_t)el*64, ln2b + (size_t)el*64);
    }
    k_proj_add<<<dim3(NROW/4), dim3(256), 0, stream>>>(XBUF, prW + (size_t)e*64, prb + e,
        out + (size_t)e*NROW);
  }
}

// Round 3
// 6814.201 us; speedup vs baseline: 1.6196x; 1.2593x over previous
//
#include <hip/hip_runtime.h>
#include <math.h>

// Problem constants
#define NN   307
#define TT   256
#define HHH  64
#define NROW (NN*TT)     // 78592
#define NBLK_D 77        // ceil(307/4) blocks per direction
#define SCANB  154       // total scan blocks (2 directions)

// ---------------- helpers ----------------
__device__ __forceinline__ float wsum(float v){
#pragma unroll
  for (int off = 32; off > 0; off >>= 1) v += __shfl_xor(v, off, 64);
  return v;
}
__device__ __forceinline__ float ftanh(float x){
  x = fminf(20.f, fmaxf(-20.f, x));
  float e = __expf(2.f*x);
  return (e - 1.f)/(e + 1.f);
}
__device__ __forceinline__ float fsigm(float x){ return 1.f/(1.f + __expf(-x)); }

// ---------------- prep kernels ----------------
__global__ void k_sparse(const float* __restrict__ A, int* __restrict__ cnt,
                         int* __restrict__ idx, float* __restrict__ val){
  int n = blockIdx.x*64 + threadIdx.x;
  if (n >= NN) return;
  int c = 0;
  for (int m = 0; m < NN; m++){
    float a = A[n*NN + m];
    if (a != 0.f){ idx[n*NN + c] = m; val[n*NN + c] = a; c++; }
  }
  cnt[n] = c;
}

__global__ void k_tr_cheb(const float* __restrict__ W0, const float* __restrict__ W1,
                          float* __restrict__ W0T, float* __restrict__ W1T){
  int t = blockIdx.x*256 + threadIdx.x;
  if (t >= 2*67*256) return;
  int c = t & 255; int rest = t >> 8; int i = rest % 67; int d = rest / 67;
  int p = c >> 6, o = c & 63;
  int src = ((d*4 + p)*64 + o)*67 + i;
  W0T[t] = W0[src];
  W1T[t] = W1[src];
}

__global__ void k_tr_gru(const float* __restrict__ Wih, const float* __restrict__ Whh,
                         float* __restrict__ WihT, float* __restrict__ WhhT){
  int t = blockIdx.x*256 + threadIdx.x;
  if (t < 2*66*192){
    int j = t % 192; int rest = t / 192; int i = rest % 66; int d = rest / 66;
    WihT[t] = Wih[(d*192 + j)*66 + i];
  }
  if (t < 2*64*192){
    int j = t % 192; int rest = t / 192; int i = rest % 64; int d = rest / 64;
    WhhT[t] = Whh[(d*192 + j)*64 + i];
  }
}

__global__ void k_af(const float* __restrict__ mseq, const float* __restrict__ tfr,
                     const float* __restrict__ tjm, const int* __restrict__ cnt,
                     const int* __restrict__ idx, const float* __restrict__ val,
                     float* __restrict__ AF){
  int n = blockIdx.x, c = blockIdx.y, t = threadIdx.x;
  const float* feat = (c == 0) ? mseq : (c == 1) ? tfr : tjm;
  float acc = 0.f; int k = cnt[n];
  for (int s = 0; s < k; s++) acc += val[n*NN + s] * feat[idx[n*NN + s]*TT + t];
  AF[((size_t)c*NN + n)*TT + t] = acc;
}

// ---------------- recurrent scan (persistent; fence-free write-through h exchange) ----
__global__ __launch_bounds__(256, 1)
void k_scan(const float* __restrict__ xseq, const float* __restrict__ mseq,
            const float* __restrict__ tfr, const float* __restrict__ tjm,
            const float* __restrict__ W0T, const float* __restrict__ W1T,
            const float* __restrict__ b0g,
            const float* __restrict__ mixW, const float* __restrict__ mixb,
            const float* __restrict__ WihT, const float* __restrict__ WhhT,
            const float* __restrict__ bih, const float* __restrict__ bhh,
            const float* __restrict__ outW, const float* __restrict__ outb,
            const float* __restrict__ jamW, const float* __restrict__ jamb,
            const int* __restrict__ spcnt, const int* __restrict__ spidx,
            const float* __restrict__ spval, const float* __restrict__ AF,
            float* __restrict__ Hseq, float* __restrict__ PRED, float* __restrict__ JPRED,
            int* __restrict__ bar)   // bar[0..1]=arrive cnt per dir, bar[16..17]=gen per dir
{
  const int tid = threadIdx.x;
  const int bid = blockIdx.x;
  const int d   = bid / NBLK_D;
  const int n0  = (bid % NBLK_D) * 4;
  const int lane = tid & 63;
  const int wid  = tid >> 6;

  int* cnt_p = bar + d;        // arrive counter (monotonic)
  int* gen_p = bar + 16 + d;   // generation word (monotonic)

  __shared__ __align__(16) float hsT[68][4];    // msg_in: rows 0..63 = h, 64..66 = feats
  __shared__ __align__(16) float amsT[68][4];   // am (67 cols)
  __shared__ __align__(16) float msgsT[64][4];
  __shared__ float malls[256][5];
  __shared__ float gis[4][192];
  __shared__ float ghs[4][192];
  __shared__ float mixs[4][4];
  __shared__ float xss[4], mss[4];
  __shared__ int   s_idx[4][320];
  __shared__ float s_val[4][320];
  __shared__ int   s_cnt[4];

  // -------- weight preload into registers (read once, reused 256 steps) --------
  float w0r[67], w1r[67];
#pragma unroll
  for (int i = 0; i < 67; i++){
    w0r[i] = W0T[(d*67 + i)*256 + tid];
    w1r[i] = W1T[(d*67 + i)*256 + tid];
  }
  const float b0r = b0g[d*256 + tid];
  float wih_r[64], whh_r[64];
  float wih64 = 0.f, wih65 = 0.f, bih_r = 0.f, bhh_r = 0.f;
  if (tid < 192){
#pragma unroll
    for (int i = 0; i < 64; i++){
      whh_r[i] = WhhT[(d*64 + i)*192 + tid];
      wih_r[i] = WihT[(d*66 + i)*192 + tid];
    }
    wih64 = WihT[(d*66 + 64)*192 + tid];
    wih65 = WihT[(d*66 + 65)*192 + tid];
    bih_r = bih[d*192 + tid];
    bhh_r = bhh[d*192 + tid];
  }
  float mixw_r[4];
#pragma unroll
  for (int p = 0; p < 4; p++) mixw_r[p] = mixW[(d*4 + p)*64 + lane];
  const float mixb0 = mixb[d*4+0], mixb1 = mixb[d*4+1], mixb2 = mixb[d*4+2], mixb3 = mixb[d*4+3];
  const float outw_r = outW[d*64 + lane], jamw_r = jamW[d*64 + lane];
  const float outb_r = outb[d], jamb_r = jamb[d];

  // -------- sparse neighbor lists into LDS (padded to x8); zero h --------
  for (int r = 0; r < 4; r++){
    const int n = min(n0 + r, NN-1);
    const int cc = spcnt[n];
    const int ccp = (cc + 7) & ~7;
    if (tid == 0) s_cnt[r] = ccp;
    for (int s = tid; s < ccp; s += 256){
      s_idx[r][s] = (s < cc) ? spidx[n*NN + s] : 0;
      s_val[r][s] = (s < cc) ? spval[n*NN + s] : 0.f;
    }
  }
  hsT[lane][wid] = 0.f;
  __syncthreads();

#pragma unroll 1
  for (int k = 0; k < TT; k++){
    const int ts = (d == 0) ? k : (TT-1 - k);
    // phase 0: time-step scalars
    if (tid < 4){
      const int r = tid; const int n = min(n0 + r, NN-1);
      const float mv = mseq[n*TT + ts];
      hsT[64][r] = mv;
      hsT[65][r] = tfr[n*TT + ts];
      hsT[66][r] = tjm[n*TT + ts];
      amsT[64][r] = AF[(0*NN + n)*TT + ts];
      amsT[65][r] = AF[(1*NN + n)*TT + ts];
      amsT[66][r] = AF[(2*NN + n)*TT + ts];
      xss[r] = xseq[n*TT + ts];
      mss[r] = mv;
    }
    // phase 1: am = sparse Anorm @ h_prev (lane = feature, wave = row)
    // loads are agent-scope (L2-bypass) so they see other XCDs' write-through stores
    {
      const float* Hprev = Hseq + (size_t)(d*257 + k)*NN*64;
      const int r = wid;
      const int ccp = s_cnt[r];
      float acc = 0.f;
      for (int s = 0; s < ccp; s += 8){
        int mI[8]; float aV[8], hV[8];
#pragma unroll
        for (int u = 0; u < 8; u++){ mI[u] = s_idx[r][s+u]; aV[u] = s_val[r][s+u]; }
#pragma unroll
        for (int u = 0; u < 8; u++)
          hV[u] = __hip_atomic_load(&Hprev[(size_t)mI[u]*64 + lane],
                                    __ATOMIC_RELAXED, __HIP_MEMORY_SCOPE_AGENT);
#pragma unroll
        for (int u = 0; u < 8; u++) acc += aV[u]*hV[u];
      }
      amsT[lane][r] = acc;
    }
    // phase 2: mix = softmax(h @ mixW^T + mixb)
    {
      const int r = wid;
      const float hv = hsT[lane][r];
      float l0 = wsum(hv * mixw_r[0]) + mixb0;
      float l1 = wsum(hv * mixw_r[1]) + mixb1;
      float l2 = wsum(hv * mixw_r[2]) + mixb2;
      float l3 = wsum(hv * mixw_r[3]) + mixb3;
      const float mx = fmaxf(fmaxf(l0,l1), fmaxf(l2,l3));
      const float e0 = __expf(l0-mx), e1 = __expf(l1-mx), e2 = __expf(l2-mx), e3 = __expf(l3-mx);
      const float inv = 1.f/(e0+e1+e2+e3);
      if (lane == 0){
        mixs[0][r] = e0*inv; mixs[1][r] = e1*inv; mixs[2][r] = e2*inv; mixs[3][r] = e3*inv;
      }
    }
    __syncthreads();
    // phase 3: m_all = tanh(msg_in@W0^T + am@W1^T + b0), scaled by mix
    {
      const int p = tid >> 6;
      float a0 = b0r, a1 = b0r, a2 = b0r, a3 = b0r;
#pragma unroll
      for (int i = 0; i < 67; i++){
        const float4 h4 = *(const float4*)&hsT[i][0];
        const float4 m4 = *(const float4*)&amsT[i][0];
        const float w0 = w0r[i], w1 = w1r[i];
        a0 += h4.x*w0 + m4.x*w1;
        a1 += h4.y*w0 + m4.y*w1;
        a2 += h4.z*w0 + m4.z*w1;
        a3 += h4.w*w0 + m4.w*w1;
      }
      malls[tid][0] = mixs[p][0]*ftanh(a0);
      malls[tid][1] = mixs[p][1]*ftanh(a1);
      malls[tid][2] = mixs[p][2]*ftanh(a2);
      malls[tid][3] = mixs[p][3]*ftanh(a3);
    }
    __syncthreads();
    // phase 3b: msg = sum_p m_all[p][:]
    msgsT[lane][wid] = malls[lane][wid] + malls[64+lane][wid] + malls[128+lane][wid] + malls[192+lane][wid];
    __syncthreads();
    // phase 4: gi, gh (thread = gate column j)
    if (tid < 192){
      float g0 = bhh_r, g1 = bhh_r, g2 = bhh_r, g3 = bhh_r;
#pragma unroll
      for (int i = 0; i < 64; i++){
        const float4 h4 = *(const float4*)&hsT[i][0];
        const float w = whh_r[i];
        g0 += h4.x*w; g1 += h4.y*w; g2 += h4.z*w; g3 += h4.w*w;
      }
      ghs[0][tid] = g0; ghs[1][tid] = g1; ghs[2][tid] = g2; ghs[3][tid] = g3;
      float q0 = bih_r + (xss[0]*mss[0])*wih64 + mss[0]*wih65;
      float q1 = bih_r + (xss[1]*mss[1])*wih64 + mss[1]*wih65;
      float q2 = bih_r + (xss[2]*mss[2])*wih64 + mss[2]*wih65;
      float q3 = bih_r + (xss[3]*mss[3])*wih64 + mss[3]*wih65;
#pragma unroll
      for (int i = 0; i < 64; i++){
        const float4 m4 = *(const float4*)&msgsT[i][0];
        const float w = wih_r[i];
        q0 += m4.x*w; q1 += m4.y*w; q2 += m4.z*w; q3 += m4.w*w;
      }
      gis[0][tid] = q0; gis[1][tid] = q1; gis[2][tid] = q2; gis[3][tid] = q3;
    }
    __syncthreads();
    // phase 5: GRU update + write-through h store (agent scope, no L2 dirty line)
    {
      const int r = wid, o = lane;
      const float ir = gis[r][o], iz = gis[r][o+64], in_ = gis[r][o+128];
      const float hr = ghs[r][o], hz = ghs[r][o+64], hn = ghs[r][o+128];
      const float rr = fsigm(ir + hr);
      const float zz = fsigm(iz + hz);
      const float nnv = ftanh(in_ + rr*hn);
      const float hold = hsT[o][r];
      const float h2 = (1.f - zz)*nnv + zz*hold + 0.1f*hold;
      hsT[o][r] = h2;
      const int n = n0 + r;
      if (n < NN)
        __hip_atomic_store(&Hseq[((size_t)(d*257 + k + 1)*NN + n)*64 + o], h2,
                           __ATOMIC_RELAXED, __HIP_MEMORY_SCOPE_AGENT);
    }
    __syncthreads();   // per-wave vmcnt(0) before s_barrier => all h stores visible
    // phase 6: pred/jam (consumed only after kernel end)
    {
      const float h2 = hsT[lane][wid];
      const float pv = wsum(h2 * outw_r);
      const float jv = wsum(h2 * jamw_r);
      const int n = n0 + wid;
      if (lane == 0 && n < NN){
        PRED [(d*NN + n)*TT + ts] = pv + outb_r;
        JPRED[(d*NN + n)*TT + ts] = jv + jamb_r;
      }
    }
    // -------- grid barrier: counter + generation, per direction, no fences ------
    if (tid == 0){
      const int prev = __hip_atomic_fetch_add(cnt_p, 1, __ATOMIC_RELAXED,
                                              __HIP_MEMORY_SCOPE_AGENT);
      if (prev == NBLK_D*(k+1) - 1){
        __hip_atomic_store(gen_p, k+1, __ATOMIC_RELAXED, __HIP_MEMORY_SCOPE_AGENT);
      } else {
        while (__hip_atomic_load(gen_p, __ATOMIC_RELAXED,
                                 __HIP_MEMORY_SCOPE_AGENT) < k+1)
          __builtin_amdgcn_s_sleep(1);
      }
    }
    __syncthreads();
  }
}

// ---------------- fusion: weights, cell outputs (x0.7), h_fused + pos-enc ----------------
__global__ __launch_bounds__(256)
void k_fusion(const float* __restrict__ PRED, const float* __restrict__ JPRED,
              const float* __restrict__ Hseq,
              const float* __restrict__ fw1, const float* __restrict__ fb1,
              const float* __restrict__ fw2, const float* __restrict__ fb2,
              float* __restrict__ x0, float* __restrict__ outp)
{
  const int tid = threadIdx.x;
  const int rr = tid >> 6, lane = tid & 63;
  const int idx = blockIdx.x*4 + rr;
  const int n = idx >> 8, t = idx & 255;
  const float pf = PRED[(0*NN + n)*TT + t], pb = PRED[(NN + n)*TT + t];
  const float jf = JPRED[(0*NN + n)*TT + t], jb = JPRED[(NN + n)*TT + t];
  const float hid = fmaxf(fw1[lane*2]*pf + fw1[lane*2+1]*pb + fb1[lane], 0.f);
  const float l0 = wsum(hid * fw2[lane]) + fb2[0];
  const float l1 = wsum(hid * fw2[64+lane]) + fb2[1];
  const float mx = fmaxf(l0,l1);
  const float e0 = __expf(l0-mx), e1 = __expf(l1-mx);
  const float inv = 1.f/(e0+e1);
  const float w0 = e0*inv, w1 = e1*inv;
  const float hf = Hseq[((size_t)(0*257 + t + 1)*NN + n)*64 + lane];
  const float hb = Hseq[((size_t)(257 + 256 - t)*NN + n)*64 + lane];
  const int i2 = lane & ~1;
  const float dv = powf(10000.f, (float)i2 * (1.f/64.f));
  const float arg = (float)t / dv;
  const float pe = (lane & 1) ? cosf(arg) : sinf(arg);
  x0[(size_t)idx*64 + lane] = hf*w0 + hb*w1 + pe;
  if (lane == 0){
    outp[idx]        = 0.7f*(w0*pf + w1*pb);
    outp[NROW + idx] = 0.7f*(w0*jf + w1*jb);
  }
}

// ---------------- tiled fp32 GEMM: Y = act(X @ W^T + b) ----------------
__global__ __launch_bounds__(256)
void k_linear(const float* __restrict__ X, const float* __restrict__ W,
              const float* __restrict__ bias, float* __restrict__ Y,
              int K, int Nout, int act)
{
  __shared__ __align__(16) float Xs[64][68];
  __shared__ __align__(16) float Ws[64][68];
  const int tid = threadIdx.x;
  const int tx = tid & 15, ty = tid >> 4;
  const int brow = blockIdx.x*64, bcol = blockIdx.y*64;
  float acc[4][4] = {};
  for (int k0 = 0; k0 < K; k0 += 64){
    for (int i = tid; i < 64*64; i += 256){
      const int r = i >> 6, c = i & 63;
      Xs[r][c] = X[(size_t)(brow + r)*K + k0 + c];
      Ws[r][c] = W[(size_t)(bcol + r)*K + k0 + c];
    }
    __syncthreads();
#pragma unroll
    for (int kk = 0; kk < 64; kk += 4){
      float4 xv[4], wv[4];
#pragma unroll
      for (int i = 0; i < 4; i++) xv[i] = *(const float4*)&Xs[ty + 16*i][kk];
#pragma unroll
      for (int j = 0; j < 4; j++) wv[j] = *(const float4*)&Ws[tx + 16*j][kk];
#pragma unroll
      for (int i = 0; i < 4; i++)
#pragma unroll
        for (int j = 0; j < 4; j++)
          acc[i][j] += xv[i].x*wv[j].x + xv[i].y*wv[j].y + xv[i].z*wv[j].z + xv[i].w*wv[j].w;
    }
    __syncthreads();
  }
#pragma unroll
  for (int i = 0; i < 4; i++){
    const int gr = brow + ty + 16*i;
#pragma unroll
    for (int j = 0; j < 4; j++){
      const int gc = bcol + tx + 16*j;
      float v = acc[i][j] + bias[gc];
      if (act) v = fmaxf(v, 0.f);
      Y[(size_t)gr*Nout + gc] = v;
    }
  }
}

// ---------------- attention per (node, head): online softmax, thread = q-row ----------------
__global__ __launch_bounds__(256)
void k_attn(const float* __restrict__ QKV, float* __restrict__ O)
{
  const int n = blockIdx.x, h = blockIdx.y;
  const int tid = threadIdx.x;
  __shared__ __align__(16) float Ks[256][16];
  __shared__ __align__(16) float Vs[256][16];
  const float* rowp = QKV + (size_t)n*256*192 + (size_t)tid*192;
  {
    const float4* ks = (const float4*)(rowp + 64 + h*16);
    const float4* vs = (const float4*)(rowp + 128 + h*16);
    float4* kd = (float4*)&Ks[tid][0];
    float4* vd = (float4*)&Vs[tid][0];
    kd[0]=ks[0]; kd[1]=ks[1]; kd[2]=ks[2]; kd[3]=ks[3];
    vd[0]=vs[0]; vd[1]=vs[1]; vd[2]=vs[2]; vd[3]=vs[3];
  }
  float q[16];
  {
    const float4* qs = (const float4*)(rowp + h*16);
#pragma unroll
    for (int c = 0; c < 4; c++){
      float4 t = qs[c];
      q[c*4+0]=t.x*0.25f; q[c*4+1]=t.y*0.25f; q[c*4+2]=t.z*0.25f; q[c*4+3]=t.w*0.25f;
    }
  }
  __syncthreads();
  float m = -1e30f, l = 0.f, acc[16] = {};
  for (int j = 0; j < 256; j++){
    float s = 0.f;
#pragma unroll
    for (int dd = 0; dd < 16; dd++) s += q[dd]*Ks[j][dd];
    const float mn = fmaxf(m, s);
    const float corr = __expf(m - mn);
    const float p = __expf(s - mn);
    l = l*corr + p;
#pragma unroll
    for (int dd = 0; dd < 16; dd++) acc[dd] = acc[dd]*corr + p*Vs[j][dd];
    m = mn;
  }
  const float inv = 1.f/l;
  float* orow = O + ((size_t)n*256 + tid)*64 + h*16;
#pragma unroll
  for (int dd = 0; dd < 16; dd++) orow[dd] = acc[dd]*inv;
}

// ---------------- residual + LN (wave per row, lane = feature) ----------------
__global__ __launch_bounds__(256)
void k_resln(const float* __restrict__ Xin, const float* __restrict__ Y,
             const float* __restrict__ g, const float* __restrict__ b,
             float* __restrict__ Xout)
{
  const int tid = threadIdx.x;
  const int r = tid >> 6, lane = tid & 63;
  const size_t row = (size_t)blockIdx.x*4 + r;
  float v = Xin[row*64 + lane] + Y[row*64 + lane];
  const float mu = wsum(v) * (1.f/64.f);
  const float dv = v - mu;
  const float var = wsum(dv*dv) * (1.f/64.f);
  Xout[row*64 + lane] = dv * rsqrtf(var + 1e-5f) * g[lane] + b[lane];
}

// ---------------- final projection, out += 0.3*refined ----------------
__global__ __launch_bounds__(256)
void k_proj_add(const float* __restrict__ X, const float* __restrict__ pW,
                const float* __restrict__ pb, float* __restrict__ outp)
{
  const int tid = threadIdx.x;
  const int r = tid >> 6, lane = tid & 63;
  const size_t row = (size_t)blockIdx.x*4 + r;
  const float v = X[row*64 + lane] * pW[lane];
  const float s = wsum(v);
  if (lane == 0) outp[row] += 0.3f*(s + pb[0]);
}

// ---------------- host launcher ----------------
extern "C" void kernel_launch(void* const* d_in, const int* in_sizes, int n_in,
                              void* d_out, int out_size, void* d_ws, size_t ws_size,
                              hipStream_t stream)
{
  const float* x_seq = (const float*)d_in[0];
  const float* m_seq = (const float*)d_in[1];
  const float* tod_f = (const float*)d_in[2];
  const float* tod_j = (const float*)d_in[3];
  const float* Anorm = (const float*)d_in[4];
  const float* chW0  = (const float*)d_in[5];
  const float* chb0  = (const float*)d_in[6];
  const float* chW1  = (const float*)d_in[7];
  const float* mixW  = (const float*)d_in[8];
  const float* mixb  = (const float*)d_in[9];
  const float* Wih   = (const float*)d_in[10];
  const float* Whh   = (const float*)d_in[11];
  const float* bih   = (const float*)d_in[12];
  const float* bhh   = (const float*)d_in[13];
  const float* outW  = (const float*)d_in[14];
  const float* outbp = (const float*)d_in[15];
  const float* jamW  = (const float*)d_in[16];
  const float* jambp = (const float*)d_in[17];
  const float* fW1   = (const float*)d_in[18];
  const float* fb1   = (const float*)d_in[19];
  const float* fW2   = (const float*)d_in[20];
  const float* fb2   = (const float*)d_in[21];
  const float* qkvW  = (const float*)d_in[22];
  const float* qkvb  = (const float*)d_in[23];
  const float* oW    = (const float*)d_in[24];
  const float* ob    = (const float*)d_in[25];
  const float* ln1g  = (const float*)d_in[26];
  const float* ln1b  = (const float*)d_in[27];
  const float* f1W   = (const float*)d_in[28];
  const float* f1b   = (const float*)d_in[29];
  const float* f2W   = (const float*)d_in[30];
  const float* f2b   = (const float*)d_in[31];
  const float* ln2g  = (const float*)d_in[32];
  const float* ln2b  = (const float*)d_in[33];
  const float* prW   = (const float*)d_in[34];
  const float* prb   = (const float*)d_in[35];
  float* out = (float*)d_out;

  float* ws = (float*)d_ws;
  size_t off = 0;
  auto take = [&](size_t n)->float*{ float* p = ws + off; off += (n + 63) & ~(size_t)63; return p; };
  int*   bar  = (int*)take(256);
  float* W0T  = take((size_t)2*67*256);
  float* W1T  = take((size_t)2*67*256);
  float* WihT = take((size_t)2*66*192);
  float* WhhT = take((size_t)2*64*192);
  int*   spcnt = (int*)take(320);
  int*   spidx = (int*)take((size_t)NN*NN);
  float* spval = take((size_t)NN*NN);
  float* AF    = take((size_t)3*NN*TT);
  float* PRED  = take((size_t)2*NN*TT);
  float* JPRED = take((size_t)2*NN*TT);
  float* HSEQ  = take((size_t)2*257*NN*64);
  float* X0    = take((size_t)NROW*64);
  float* XBUF  = take((size_t)NROW*64);
  float* OBUF  = take((size_t)NROW*64);
  float* FBUF  = take((size_t)NROW*256);   // holds QKV (192), oproj out (64), FF1 out (256)
  (void)ws_size; (void)in_sizes; (void)n_in; (void)out_size;

  hipMemsetAsync(bar, 0, 256*sizeof(int), stream);
  hipMemsetAsync(HSEQ, 0, (size_t)NN*64*sizeof(float), stream);                     // h0 fwd
  hipMemsetAsync(HSEQ + (size_t)257*NN*64, 0, (size_t)NN*64*sizeof(float), stream); // h0 bwd

  k_sparse<<<dim3((NN+63)/64), dim3(64), 0, stream>>>(Anorm, spcnt, spidx, spval);
  k_tr_cheb<<<dim3(134), dim3(256), 0, stream>>>(chW0, chW1, W0T, W1T);
  k_tr_gru<<<dim3(99), dim3(256), 0, stream>>>(Wih, Whh, WihT, WhhT);
  k_af<<<dim3(NN,3), dim3(256), 0, stream>>>(m_seq, tod_f, tod_j, spcnt, spidx, spval, AF);

  k_scan<<<dim3(SCANB), dim3(256), 0, stream>>>(x_seq, m_seq, tod_f, tod_j, W0T, W1T,
      chb0, mixW, mixb, WihT, WhhT, bih, bhh, outW, outbp, jamW, jambp,
      spcnt, spidx, spval, AF, HSEQ, PRED, JPRED, bar);

  k_fusion<<<dim3(NROW/4), dim3(256), 0, stream>>>(PRED, JPRED, HSEQ, fW1, fb1, fW2, fb2, X0, out);

  for (int e = 0; e < 2; e++){
    for (int l = 0; l < 3; l++){
      const int el = e*3 + l;
      const float* xin = (l == 0) ? X0 : XBUF;
      // qkv: (NROW,64) @ (192,64)^T -> FBUF (192-wide)
      k_linear<<<dim3(NROW/64, 3), dim3(256), 0, stream>>>(xin, qkvW + (size_t)el*192*64,
          qkvb + (size_t)el*192, FBUF, 64, 192, 0);
      k_attn<<<dim3(NN, 4), dim3(256), 0, stream>>>(FBUF, OBUF);
      // oproj: (NROW,64) @ (64,64)^T -> FBUF (64-wide)
      k_linear<<<dim3(NROW/64, 1), dim3(256), 0, stream>>>(OBUF, oW + (size_t)el*64*64,
          ob + (size_t)el*64, FBUF, 64, 64, 0);
      k_resln<<<dim3(NROW/4), dim3(256), 0, stream>>>(xin, FBUF,
          ln1g + (size_t)el*64, ln1b + (size_t)el*64, XBUF);
      // ff1: (NROW,64) @ (256,64)^T -> FBUF (256-wide, relu)
      k_linear<<<dim3(NROW/64, 4), dim3(256), 0, stream>>>(XBUF, f1W + (size_t)el*256*64,
          f1b + (size_t)el*256, FBUF, 64, 256, 1);
      // ff2: (NROW,256) @ (64,256)^T -> OBUF (64-wide)
      k_linear<<<dim3(NROW/64, 1), dim3(256), 0, stream>>>(FBUF, f2W + (size_t)el*64*256,
          f2b + (size_t)el*64, OBUF, 256, 64, 0);
      k_resln<<<dim3(NROW/4), dim3(256), 0, stream>>>(XBUF, OBUF,
          ln2g + (size_t)el*64, ln2b + (size_t)el*64, XBUF);
    }
    k_proj_add<<<dim3(NROW/4), dim3(256), 0, stream>>>(XBUF, prW + (size_t)e*64, prb + e,
        out + (size_t)e*NROW);
  }
}

// Round 4
// 6342.088 us; speedup vs baseline: 1.7401x; 1.0744x over previous
//
#include <hip/hip_runtime.h>
#include <math.h>

// Problem constants
#define NN   307
#define TT   256
#define HHH  64
#define NROW (NN*TT)     // 78592
#define NBLK_D 77        // ceil(307/4) blocks per direction
#define SCANB  154       // total scan blocks (2 directions)

// ---------------- helpers ----------------
__device__ __forceinline__ float wsum(float v){
#pragma unroll
  for (int off = 32; off > 0; off >>= 1) v += __shfl_xor(v, off, 64);
  return v;
}
__device__ __forceinline__ float ftanh(float x){
  x = fminf(20.f, fmaxf(-20.f, x));
  float e = __expf(2.f*x);
  return (e - 1.f)/(e + 1.f);
}
__device__ __forceinline__ float fsigm(float x){ return 1.f/(1.f + __expf(-x)); }

// ---------------- prep kernels ----------------
__global__ void k_sparse(const float* __restrict__ A, int* __restrict__ cnt,
                         int* __restrict__ idx, float* __restrict__ val){
  int n = blockIdx.x*64 + threadIdx.x;
  if (n >= NN) return;
  int c = 0;
  for (int m = 0; m < NN; m++){
    float a = A[n*NN + m];
    if (a != 0.f){ idx[n*NN + c] = m; val[n*NN + c] = a; c++; }
  }
  cnt[n] = c;
}

__global__ void k_tr_cheb(const float* __restrict__ W0, const float* __restrict__ W1,
                          float* __restrict__ W0T, float* __restrict__ W1T){
  int t = blockIdx.x*256 + threadIdx.x;
  if (t >= 2*67*256) return;
  int c = t & 255; int rest = t >> 8; int i = rest % 67; int d = rest / 67;
  int p = c >> 6, o = c & 63;
  int src = ((d*4 + p)*64 + o)*67 + i;
  W0T[t] = W0[src];
  W1T[t] = W1[src];
}

__global__ void k_tr_gru(const float* __restrict__ Wih, const float* __restrict__ Whh,
                         float* __restrict__ WihT, float* __restrict__ WhhT){
  int t = blockIdx.x*256 + threadIdx.x;
  if (t < 2*66*192){
    int j = t % 192; int rest = t / 192; int i = rest % 66; int d = rest / 66;
    WihT[t] = Wih[(d*192 + j)*66 + i];
  }
  if (t < 2*64*192){
    int j = t % 192; int rest = t / 192; int i = rest % 64; int d = rest / 64;
    WhhT[t] = Whh[(d*192 + j)*64 + i];
  }
}

__global__ void k_af(const float* __restrict__ mseq, const float* __restrict__ tfr,
                     const float* __restrict__ tjm, const int* __restrict__ cnt,
                     const int* __restrict__ idx, const float* __restrict__ val,
                     float* __restrict__ AF){
  int n = blockIdx.x, c = blockIdx.y, t = threadIdx.x;
  const float* feat = (c == 0) ? mseq : (c == 1) ? tfr : tjm;
  float acc = 0.f; int k = cnt[n];
  for (int s = 0; s < k; s++) acc += val[n*NN + s] * feat[idx[n*NN + s]*TT + t];
  AF[((size_t)c*NN + n)*TT + t] = acc;
}

// ---------------- recurrent scan (persistent; per-block flag barrier, no RMW) ----
__global__ __launch_bounds__(256, 1)
void k_scan(const float* __restrict__ xseq, const float* __restrict__ mseq,
            const float* __restrict__ tfr, const float* __restrict__ tjm,
            const float* __restrict__ W0T, const float* __restrict__ W1T,
            const float* __restrict__ b0g,
            const float* __restrict__ mixW, const float* __restrict__ mixb,
            const float* __restrict__ WihT, const float* __restrict__ WhhT,
            const float* __restrict__ bih, const float* __restrict__ bhh,
            const float* __restrict__ outW, const float* __restrict__ outb,
            const float* __restrict__ jamW, const float* __restrict__ jamb,
            const int* __restrict__ spcnt, const int* __restrict__ spidx,
            const float* __restrict__ spval, const float* __restrict__ AF,
            float* __restrict__ Hseq, float* __restrict__ PRED, float* __restrict__ JPRED,
            int* __restrict__ slots)   // slots[bid] = step counter, per block (no RMW)
{
  const int tid = threadIdx.x;
  const int bid = blockIdx.x;
  const int d   = bid / NBLK_D;
  const int n0  = (bid % NBLK_D) * 4;
  const int lane = tid & 63;
  const int wid  = tid >> 6;

  __shared__ __align__(16) float hsT[68][4];    // msg_in: rows 0..63 = h, 64..66 = feats
  __shared__ __align__(16) float amsT[68][4];   // am (67 cols)
  __shared__ __align__(16) float msgsT[64][4];
  __shared__ float malls[256][5];
  __shared__ float gis[4][192];
  __shared__ float ghs[4][192];
  __shared__ float mixs[4][4];
  __shared__ float xss[4], mss[4];
  __shared__ int   s_idx[4][320];
  __shared__ float s_val[4][320];
  __shared__ int   s_cnt[4];

  // -------- weight preload into registers (read once, reused 256 steps) --------
  float w0r[67], w1r[67];
#pragma unroll
  for (int i = 0; i < 67; i++){
    w0r[i] = W0T[(d*67 + i)*256 + tid];
    w1r[i] = W1T[(d*67 + i)*256 + tid];
  }
  const float b0r = b0g[d*256 + tid];
  float wih_r[64], whh_r[64];
  float wih64 = 0.f, wih65 = 0.f, bih_r = 0.f, bhh_r = 0.f;
  if (tid < 192){
#pragma unroll
    for (int i = 0; i < 64; i++){
      whh_r[i] = WhhT[(d*64 + i)*192 + tid];
      wih_r[i] = WihT[(d*66 + i)*192 + tid];
    }
    wih64 = WihT[(d*66 + 64)*192 + tid];
    wih65 = WihT[(d*66 + 65)*192 + tid];
    bih_r = bih[d*192 + tid];
    bhh_r = bhh[d*192 + tid];
  }
  float mixw_r[4];
#pragma unroll
  for (int p = 0; p < 4; p++) mixw_r[p] = mixW[(d*4 + p)*64 + lane];
  const float mixb0 = mixb[d*4+0], mixb1 = mixb[d*4+1], mixb2 = mixb[d*4+2], mixb3 = mixb[d*4+3];
  const float outw_r = outW[d*64 + lane], jamw_r = jamW[d*64 + lane];
  const float outb_r = outb[d], jamb_r = jamb[d];

  // -------- sparse neighbor lists into LDS (padded to x16); zero h --------
  for (int r = 0; r < 4; r++){
    const int n = min(n0 + r, NN-1);
    const int cc = spcnt[n];
    const int ccp = (cc + 15) & ~15;
    if (tid == 0) s_cnt[r] = ccp;
    for (int s = tid; s < ccp; s += 256){
      s_idx[r][s] = (s < cc) ? spidx[n*NN + s] : 0;
      s_val[r][s] = (s < cc) ? spval[n*NN + s] : 0.f;
    }
  }
  hsT[lane][wid] = 0.f;
  __syncthreads();

#pragma unroll 1
  for (int k = 0; k < TT; k++){
    const int ts = (d == 0) ? k : (TT-1 - k);
    // phase 0: time-step scalars
    if (tid < 4){
      const int r = tid; const int n = min(n0 + r, NN-1);
      const float mv = mseq[n*TT + ts];
      hsT[64][r] = mv;
      hsT[65][r] = tfr[n*TT + ts];
      hsT[66][r] = tjm[n*TT + ts];
      amsT[64][r] = AF[(0*NN + n)*TT + ts];
      amsT[65][r] = AF[(1*NN + n)*TT + ts];
      amsT[66][r] = AF[(2*NN + n)*TT + ts];
      xss[r] = xseq[n*TT + ts];
      mss[r] = mv;
    }
    // phase 1: am = sparse Anorm @ h_prev (lane = feature, wave = row)
    // 16 loads in flight per batch: one exposed latency for the typical row
    {
      const float* Hprev = Hseq + (size_t)(d*257 + k)*NN*64;
      const int r = wid;
      const int ccp = s_cnt[r];
      float acc = 0.f;
      for (int s = 0; s < ccp; s += 16){
        float aV[16], hV[16];
#pragma unroll
        for (int u = 0; u < 16; u++){
          const int m = s_idx[r][s+u];
          aV[u] = s_val[r][s+u];
          hV[u] = __hip_atomic_load(&Hprev[(size_t)m*64 + lane],
                                    __ATOMIC_RELAXED, __HIP_MEMORY_SCOPE_AGENT);
        }
#pragma unroll
        for (int u = 0; u < 16; u++) acc += aV[u]*hV[u];
      }
      amsT[lane][r] = acc;
    }
    // phase 2: mix = softmax(h @ mixW^T + mixb)
    {
      const int r = wid;
      const float hv = hsT[lane][r];
      float l0 = wsum(hv * mixw_r[0]) + mixb0;
      float l1 = wsum(hv * mixw_r[1]) + mixb1;
      float l2 = wsum(hv * mixw_r[2]) + mixb2;
      float l3 = wsum(hv * mixw_r[3]) + mixb3;
      const float mx = fmaxf(fmaxf(l0,l1), fmaxf(l2,l3));
      const float e0 = __expf(l0-mx), e1 = __expf(l1-mx), e2 = __expf(l2-mx), e3 = __expf(l3-mx);
      const float inv = 1.f/(e0+e1+e2+e3);
      if (lane == 0){
        mixs[0][r] = e0*inv; mixs[1][r] = e1*inv; mixs[2][r] = e2*inv; mixs[3][r] = e3*inv;
      }
    }
    __syncthreads();
    // phase 3: m_all = tanh(msg_in@W0^T + am@W1^T + b0), scaled by mix
    {
      const int p = tid >> 6;
      float a0 = b0r, a1 = b0r, a2 = b0r, a3 = b0r;
#pragma unroll
      for (int i = 0; i < 67; i++){
        const float4 h4 = *(const float4*)&hsT[i][0];
        const float4 m4 = *(const float4*)&amsT[i][0];
        const float w0 = w0r[i], w1 = w1r[i];
        a0 += h4.x*w0 + m4.x*w1;
        a1 += h4.y*w0 + m4.y*w1;
        a2 += h4.z*w0 + m4.z*w1;
        a3 += h4.w*w0 + m4.w*w1;
      }
      malls[tid][0] = mixs[p][0]*ftanh(a0);
      malls[tid][1] = mixs[p][1]*ftanh(a1);
      malls[tid][2] = mixs[p][2]*ftanh(a2);
      malls[tid][3] = mixs[p][3]*ftanh(a3);
    }
    __syncthreads();
    // phase 3b: msg = sum_p m_all[p][:]
    msgsT[lane][wid] = malls[lane][wid] + malls[64+lane][wid] + malls[128+lane][wid] + malls[192+lane][wid];
    __syncthreads();
    // phase 4: gi, gh (thread = gate column j)
    if (tid < 192){
      float g0 = bhh_r, g1 = bhh_r, g2 = bhh_r, g3 = bhh_r;
#pragma unroll
      for (int i = 0; i < 64; i++){
        const float4 h4 = *(const float4*)&hsT[i][0];
        const float w = whh_r[i];
        g0 += h4.x*w; g1 += h4.y*w; g2 += h4.z*w; g3 += h4.w*w;
      }
      ghs[0][tid] = g0; ghs[1][tid] = g1; ghs[2][tid] = g2; ghs[3][tid] = g3;
      float q0 = bih_r + (xss[0]*mss[0])*wih64 + mss[0]*wih65;
      float q1 = bih_r + (xss[1]*mss[1])*wih64 + mss[1]*wih65;
      float q2 = bih_r + (xss[2]*mss[2])*wih64 + mss[2]*wih65;
      float q3 = bih_r + (xss[3]*mss[3])*wih64 + mss[3]*wih65;
#pragma unroll
      for (int i = 0; i < 64; i++){
        const float4 m4 = *(const float4*)&msgsT[i][0];
        const float w = wih_r[i];
        q0 += m4.x*w; q1 += m4.y*w; q2 += m4.z*w; q3 += m4.w*w;
      }
      gis[0][tid] = q0; gis[1][tid] = q1; gis[2][tid] = q2; gis[3][tid] = q3;
    }
    __syncthreads();
    // phase 5: GRU update + write-through h store (agent scope)
    {
      const int r = wid, o = lane;
      const float ir = gis[r][o], iz = gis[r][o+64], in_ = gis[r][o+128];
      const float hr = ghs[r][o], hz = ghs[r][o+64], hn = ghs[r][o+128];
      const float rr = fsigm(ir + hr);
      const float zz = fsigm(iz + hz);
      const float nnv = ftanh(in_ + rr*hn);
      const float hold = hsT[o][r];
      const float h2 = (1.f - zz)*nnv + zz*hold + 0.1f*hold;
      hsT[o][r] = h2;
      const int n = n0 + r;
      if (n < NN)
        __hip_atomic_store(&Hseq[((size_t)(d*257 + k + 1)*NN + n)*64 + o], h2,
                           __ATOMIC_RELAXED, __HIP_MEMORY_SCOPE_AGENT);
    }
    __syncthreads();   // per-wave vmcnt(0) before s_barrier => all h stores visible
    // arrive: publish own flag ASAP (no RMW — 77 independent write-through stores)
    if (tid == 0)
      __hip_atomic_store(&slots[bid], k + 1, __ATOMIC_RELAXED, __HIP_MEMORY_SCOPE_AGENT);
    // phase 6: pred/jam (overlaps flag-store visibility latency)
    {
      const float h2 = hsT[lane][wid];
      const float pv = wsum(h2 * outw_r);
      const float jv = wsum(h2 * jamw_r);
      const int n = n0 + wid;
      if (lane == 0 && n < NN){
        PRED [(d*NN + n)*TT + ts] = pv + outb_r;
        JPRED[(d*NN + n)*TT + ts] = jv + jamb_r;
      }
    }
    // wait: wave 0 lane-parallel poll of this direction's 77 flags (1-2 coalesced loads)
    if (tid < 64){
      const int* sl = slots + d*NBLK_D;
      const int i2 = lane + 64;
      for (;;){
        const int a = __hip_atomic_load(&sl[lane], __ATOMIC_RELAXED,
                                        __HIP_MEMORY_SCOPE_AGENT);
        const int b = (i2 < NBLK_D)
            ? __hip_atomic_load(&sl[i2], __ATOMIC_RELAXED, __HIP_MEMORY_SCOPE_AGENT)
            : 0x7fffffff;
        if (__all(min(a, b) >= k + 1)) break;
        __builtin_amdgcn_s_sleep(1);
      }
    }
    __syncthreads();
  }
}

// ---------------- fusion: weights, cell outputs (x0.7), h_fused + pos-enc ----------------
__global__ __launch_bounds__(256)
void k_fusion(const float* __restrict__ PRED, const float* __restrict__ JPRED,
              const float* __restrict__ Hseq,
              const float* __restrict__ fw1, const float* __restrict__ fb1,
              const float* __restrict__ fw2, const float* __restrict__ fb2,
              float* __restrict__ x0, float* __restrict__ outp)
{
  const int tid = threadIdx.x;
  const int rr = tid >> 6, lane = tid & 63;
  const int idx = blockIdx.x*4 + rr;
  const int n = idx >> 8, t = idx & 255;
  const float pf = PRED[(0*NN + n)*TT + t], pb = PRED[(NN + n)*TT + t];
  const float jf = JPRED[(0*NN + n)*TT + t], jb = JPRED[(NN + n)*TT + t];
  const float hid = fmaxf(fw1[lane*2]*pf + fw1[lane*2+1]*pb + fb1[lane], 0.f);
  const float l0 = wsum(hid * fw2[lane]) + fb2[0];
  const float l1 = wsum(hid * fw2[64+lane]) + fb2[1];
  const float mx = fmaxf(l0,l1);
  const float e0 = __expf(l0-mx), e1 = __expf(l1-mx);
  const float inv = 1.f/(e0+e1);
  const float w0 = e0*inv, w1 = e1*inv;
  const float hf = Hseq[((size_t)(0*257 + t + 1)*NN + n)*64 + lane];
  const float hb = Hseq[((size_t)(257 + 256 - t)*NN + n)*64 + lane];
  const int i2 = lane & ~1;
  const float dv = powf(10000.f, (float)i2 * (1.f/64.f));
  const float arg = (float)t / dv;
  const float pe = (lane & 1) ? cosf(arg) : sinf(arg);
  x0[(size_t)idx*64 + lane] = hf*w0 + hb*w1 + pe;
  if (lane == 0){
    outp[idx]        = 0.7f*(w0*pf + w1*pb);
    outp[NROW + idx] = 0.7f*(w0*jf + w1*jb);
  }
}

// ---------------- tiled fp32 GEMM: Y = act(X @ W^T + b) ----------------
__global__ __launch_bounds__(256)
void k_linear(const float* __restrict__ X, const float* __restrict__ W,
              const float* __restrict__ bias, float* __restrict__ Y,
              int K, int Nout, int act)
{
  __shared__ __align__(16) float Xs[64][68];
  __shared__ __align__(16) float Ws[64][68];
  const int tid = threadIdx.x;
  const int tx = tid & 15, ty = tid >> 4;
  const int brow = blockIdx.x*64, bcol = blockIdx.y*64;
  float acc[4][4] = {};
  for (int k0 = 0; k0 < K; k0 += 64){
    for (int i = tid; i < 64*64; i += 256){
      const int r = i >> 6, c = i & 63;
      Xs[r][c] = X[(size_t)(brow + r)*K + k0 + c];
      Ws[r][c] = W[(size_t)(bcol + r)*K + k0 + c];
    }
    __syncthreads();
#pragma unroll
    for (int kk = 0; kk < 64; kk += 4){
      float4 xv[4], wv[4];
#pragma unroll
      for (int i = 0; i < 4; i++) xv[i] = *(const float4*)&Xs[ty + 16*i][kk];
#pragma unroll
      for (int j = 0; j < 4; j++) wv[j] = *(const float4*)&Ws[tx + 16*j][kk];
#pragma unroll
      for (int i = 0; i < 4; i++)
#pragma unroll
        for (int j = 0; j < 4; j++)
          acc[i][j] += xv[i].x*wv[j].x + xv[i].y*wv[j].y + xv[i].z*wv[j].z + xv[i].w*wv[j].w;
    }
    __syncthreads();
  }
#pragma unroll
  for (int i = 0; i < 4; i++){
    const int gr = brow + ty + 16*i;
#pragma unroll
    for (int j = 0; j < 4; j++){
      const int gc = bcol + tx + 16*j;
      float v = acc[i][j] + bias[gc];
      if (act) v = fmaxf(v, 0.f);
      Y[(size_t)gr*Nout + gc] = v;
    }
  }
}

// ---------------- attention per (node, head): online softmax, thread = q-row ----------------
__global__ __launch_bounds__(256)
void k_attn(const float* __restrict__ QKV, float* __restrict__ O)
{
  const int n = blockIdx.x, h = blockIdx.y;
  const int tid = threadIdx.x;
  __shared__ __align__(16) float Ks[256][16];
  __shared__ __align__(16) float Vs[256][16];
  const float* rowp = QKV + (size_t)n*256*192 + (size_t)tid*192;
  {
    const float4* ks = (const float4*)(rowp + 64 + h*16);
    const float4* vs = (const float4*)(rowp + 128 + h*16);
    float4* kd = (float4*)&Ks[tid][0];
    float4* vd = (float4*)&Vs[tid][0];
    kd[0]=ks[0]; kd[1]=ks[1]; kd[2]=ks[2]; kd[3]=ks[3];
    vd[0]=vs[0]; vd[1]=vs[1]; vd[2]=vs[2]; vd[3]=vs[3];
  }
  float q[16];
  {
    const float4* qs = (const float4*)(rowp + h*16);
#pragma unroll
    for (int c = 0; c < 4; c++){
      float4 t = qs[c];
      q[c*4+0]=t.x*0.25f; q[c*4+1]=t.y*0.25f; q[c*4+2]=t.z*0.25f; q[c*4+3]=t.w*0.25f;
    }
  }
  __syncthreads();
  float m = -1e30f, l = 0.f, acc[16] = {};
  for (int j = 0; j < 256; j++){
    float s = 0.f;
#pragma unroll
    for (int dd = 0; dd < 16; dd++) s += q[dd]*Ks[j][dd];
    const float mn = fmaxf(m, s);
    const float corr = __expf(m - mn);
    const float p = __expf(s - mn);
    l = l*corr + p;
#pragma unroll
    for (int dd = 0; dd < 16; dd++) acc[dd] = acc[dd]*corr + p*Vs[j][dd];
    m = mn;
  }
  const float inv = 1.f/l;
  float* orow = O + ((size_t)n*256 + tid)*64 + h*16;
#pragma unroll
  for (int dd = 0; dd < 16; dd++) orow[dd] = acc[dd]*inv;
}

// ---------------- residual + LN (wave per row, lane = feature) ----------------
__global__ __launch_bounds__(256)
void k_resln(const float* __restrict__ Xin, const float* __restrict__ Y,
             const float* __restrict__ g, const float* __restrict__ b,
             float* __restrict__ Xout)
{
  const int tid = threadIdx.x;
  const int r = tid >> 6, lane = tid & 63;
  const size_t row = (size_t)blockIdx.x*4 + r;
  float v = Xin[row*64 + lane] + Y[row*64 + lane];
  const float mu = wsum(v) * (1.f/64.f);
  const float dv = v - mu;
  const float var = wsum(dv*dv) * (1.f/64.f);
  Xout[row*64 + lane] = dv * rsqrtf(var + 1e-5f) * g[lane] + b[lane];
}

// ---------------- final projection, out += 0.3*refined ----------------
__global__ __launch_bounds__(256)
void k_proj_add(const float* __restrict__ X, const float* __restrict__ pW,
                const float* __restrict__ pb, float* __restrict__ outp)
{
  const int tid = threadIdx.x;
  const int r = tid >> 6, lane = tid & 63;
  const size_t row = (size_t)blockIdx.x*4 + r;
  const float v = X[row*64 + lane] * pW[lane];
  const float s = wsum(v);
  if (lane == 0) outp[row] += 0.3f*(s + pb[0]);
}

// ---------------- host launcher ----------------
extern "C" void kernel_launch(void* const* d_in, const int* in_sizes, int n_in,
                              void* d_out, int out_size, void* d_ws, size_t ws_size,
                              hipStream_t stream)
{
  const float* x_seq = (const float*)d_in[0];
  const float* m_seq = (const float*)d_in[1];
  const float* tod_f = (const float*)d_in[2];
  const float* tod_j = (const float*)d_in[3];
  const float* Anorm = (const float*)d_in[4];
  const float* chW0  = (const float*)d_in[5];
  const float* chb0  = (const float*)d_in[6];
  const float* chW1  = (const float*)d_in[7];
  const float* mixW  = (const float*)d_in[8];
  const float* mixb  = (const float*)d_in[9];
  const float* Wih   = (const float*)d_in[10];
  const float* Whh   = (const float*)d_in[11];
  const float* bih   = (const float*)d_in[12];
  const float* bhh   = (const float*)d_in[13];
  const float* outW  = (const float*)d_in[14];
  const float* outbp = (const float*)d_in[15];
  const float* jamW  = (const float*)d_in[16];
  const float* jambp = (const float*)d_in[17];
  const float* fW1   = (const float*)d_in[18];
  const float* fb1   = (const float*)d_in[19];
  const float* fW2   = (const float*)d_in[20];
  const float* fb2   = (const float*)d_in[21];
  const float* qkvW  = (const float*)d_in[22];
  const float* qkvb  = (const float*)d_in[23];
  const float* oW    = (const float*)d_in[24];
  const float* ob    = (const float*)d_in[25];
  const float* ln1g  = (const float*)d_in[26];
  const float* ln1b  = (const float*)d_in[27];
  const float* f1W   = (const float*)d_in[28];
  const float* f1b   = (const float*)d_in[29];
  const float* f2W   = (const float*)d_in[30];
  const float* f2b   = (const float*)d_in[31];
  const float* ln2g  = (const float*)d_in[32];
  const float* ln2b  = (const float*)d_in[33];
  const float* prW   = (const float*)d_in[34];
  const float* prb   = (const float*)d_in[35];
  float* out = (float*)d_out;

  float* ws = (float*)d_ws;
  size_t off = 0;
  auto take = [&](size_t n)->float*{ float* p = ws + off; off += (n + 63) & ~(size_t)63; return p; };
  int*   slots = (int*)take(256);
  float* W0T  = take((size_t)2*67*256);
  float* W1T  = take((size_t)2*67*256);
  float* WihT = take((size_t)2*66*192);
  float* WhhT = take((size_t)2*64*192);
  int*   spcnt = (int*)take(320);
  int*   spidx = (int*)take((size_t)NN*NN);
  float* spval = take((size_t)NN*NN);
  float* AF    = take((size_t)3*NN*TT);
  float* PRED  = take((size_t)2*NN*TT);
  float* JPRED = take((size_t)2*NN*TT);
  float* HSEQ  = take((size_t)2*257*NN*64);
  float* X0    = take((size_t)NROW*64);
  float* XBUF  = take((size_t)NROW*64);
  float* OBUF  = take((size_t)NROW*64);
  float* FBUF  = take((size_t)NROW*256);   // holds QKV (192), oproj out (64), FF1 out (256)
  (void)ws_size; (void)in_sizes; (void)n_in; (void)out_size;

  hipMemsetAsync(slots, 0, 256*sizeof(int), stream);
  hipMemsetAsync(HSEQ, 0, (size_t)NN*64*sizeof(float), stream);                     // h0 fwd
  hipMemsetAsync(HSEQ + (size_t)257*NN*64, 0, (size_t)NN*64*sizeof(float), stream); // h0 bwd

  k_sparse<<<dim3((NN+63)/64), dim3(64), 0, stream>>>(Anorm, spcnt, spidx, spval);
  k_tr_cheb<<<dim3(134), dim3(256), 0, stream>>>(chW0, chW1, W0T, W1T);
  k_tr_gru<<<dim3(99), dim3(256), 0, stream>>>(Wih, Whh, WihT, WhhT);
  k_af<<<dim3(NN,3), dim3(256), 0, stream>>>(m_seq, tod_f, tod_j, spcnt, spidx, spval, AF);

  k_scan<<<dim3(SCANB), dim3(256), 0, stream>>>(x_seq, m_seq, tod_f, tod_j, W0T, W1T,
      chb0, mixW, mixb, WihT, WhhT, bih, bhh, outW, outbp, jamW, jambp,
      spcnt, spidx, spval, AF, HSEQ, PRED, JPRED, slots);

  k_fusion<<<dim3(NROW/4), dim3(256), 0, stream>>>(PRED, JPRED, HSEQ, fW1, fb1, fW2, fb2, X0, out);

  for (int e = 0; e < 2; e++){
    for (int l = 0; l < 3; l++){
      const int el = e*3 + l;
      const float* xin = (l == 0) ? X0 : XBUF;
      // qkv: (NROW,64) @ (192,64)^T -> FBUF (192-wide)
      k_linear<<<dim3(NROW/64, 3), dim3(256), 0, stream>>>(xin, qkvW + (size_t)el*192*64,
          qkvb + (size_t)el*192, FBUF, 64, 192, 0);
      k_attn<<<dim3(NN, 4), dim3(256), 0, stream>>>(FBUF, OBUF);
      // oproj: (NROW,64) @ (64,64)^T -> FBUF (64-wide)
      k_linear<<<dim3(NROW/64, 1), dim3(256), 0, stream>>>(OBUF, oW + (size_t)el*64*64,
          ob + (size_t)el*64, FBUF, 64, 64, 0);
      k_resln<<<dim3(NROW/4), dim3(256), 0, stream>>>(xin, FBUF,
          ln1g + (size_t)el*64, ln1b + (size_t)el*64, XBUF);
      // ff1: (NROW,64) @ (256,64)^T -> FBUF (256-wide, relu)
      k_linear<<<dim3(NROW/64, 4), dim3(256), 0, stream>>>(XBUF, f1W + (size_t)el*256*64,
          f1b + (size_t)el*256, FBUF, 64, 256, 1);
      // ff2: (NROW,256) @ (64,256)^T -> OBUF (64-wide)
      k_linear<<<dim3(NROW/64, 1), dim3(256), 0, stream>>>(FBUF, f2W + (size_t)el*64*256,
          f2b + (size_t)el*64, OBUF, 256, 64, 0);
      k_resln<<<dim3(NROW/4), dim3(256), 0, stream>>>(XBUF, OBUF,
          ln2g + (size_t)el*64, ln2b + (size_t)el*64, XBUF);
    }
    k_proj_add<<<dim3(NROW/4), dim3(256), 0, stream>>>(XBUF, prW + (size_t)e*64, prb + e,
        out + (size_t)e*NROW);
  }
}